// Round 1
// baseline (541.824 us; speedup 1.0000x reference)
//
#include <hip/hip_runtime.h>

// ---------------------------------------------------------------------------
// GCN 3-layer forward on MI355X.
// Pipeline per call (no cached state; deterministic):
//   detect int64-vs-int32 edge layout -> deg -> dinv -> scan(offs) -> CSR fill
//   -> [GEMM -> aggregate(+bias,+leakyrelu)] x3
// ---------------------------------------------------------------------------

static inline size_t alignup(size_t v, size_t a) { return (v + a - 1) & ~(a - 1); }

// --- edge dtype detect: if input is int64, every odd 32-bit word is 0 -------
__global__ void k_detect(const int* __restrict__ ei, int* __restrict__ flag) {
    int v = ei[2 * threadIdx.x + 1];            // high word if int64
    unsigned long long b = __ballot(v != 0);
    if (threadIdx.x == 0) *flag = (b == 0ull) ? 1 : 0;   // 1 => int64 layout
}

__global__ void k_zero2(int* __restrict__ a, int* __restrict__ b, int n) {
    int i = blockIdx.x * blockDim.x + threadIdx.x;
    if (i < n) { a[i] = 0; b[i] = 0; }
}

__global__ void k_deg(const int* __restrict__ ei, int E,
                      const int* __restrict__ flag, int* __restrict__ deg) {
    int i = blockIdx.x * blockDim.x + threadIdx.x;
    if (i >= E) return;
    int is64 = *flag;
    int d = is64 ? ei[2 * (E + i)] : ei[E + i];
    atomicAdd(&deg[d], 1);
}

__global__ void k_dinv(const int* __restrict__ deg, float* __restrict__ dinv, int N) {
    int i = blockIdx.x * blockDim.x + threadIdx.x;
    if (i < N) dinv[i] = rsqrtf((float)deg[i] + 1.0f);
}

// --- 3-kernel exclusive scan over deg (256 elems/block) ---------------------
__global__ void k_scan1(const int* __restrict__ deg, int* __restrict__ offs,
                        int* __restrict__ bsums, int N) {
    __shared__ int s[256];
    int i = blockIdx.x * 256 + threadIdx.x;
    int v = (i < N) ? deg[i] : 0;
    s[threadIdx.x] = v;
    __syncthreads();
    for (int off = 1; off < 256; off <<= 1) {
        int t = (threadIdx.x >= off) ? s[threadIdx.x - off] : 0;
        __syncthreads();
        s[threadIdx.x] += t;
        __syncthreads();
    }
    if (i < N) offs[i] = s[threadIdx.x] - v;   // exclusive
    if (threadIdx.x == 255) bsums[blockIdx.x] = s[255];
}

__global__ void k_scan2(const int* __restrict__ bsums, int* __restrict__ boffs, int nb) {
    __shared__ int s[256];
    int i = threadIdx.x;
    int v = (i < nb) ? bsums[i] : 0;
    s[i] = v;
    __syncthreads();
    for (int off = 1; off < 256; off <<= 1) {
        int t = (i >= off) ? s[i - off] : 0;
        __syncthreads();
        s[i] += t;
        __syncthreads();
    }
    if (i < nb) boffs[i] = s[i] - v;
}

__global__ void k_scan3(int* __restrict__ offs, const int* __restrict__ boffs,
                        int N, int E) {
    int i = blockIdx.x * blockDim.x + threadIdx.x;
    if (i < N) offs[i] += boffs[i >> 8];
    if (i == 0) offs[N] = E;
}

__global__ void k_fill(const int* __restrict__ ei, int E,
                       const int* __restrict__ flag,
                       const int* __restrict__ offs, int* __restrict__ cnt,
                       int* __restrict__ csr) {
    int i = blockIdx.x * blockDim.x + threadIdx.x;
    if (i >= E) return;
    int is64 = *flag;
    int s = is64 ? ei[2 * i] : ei[i];
    int d = is64 ? ei[2 * (E + i)] : ei[E + i];
    int slot = offs[d] + atomicAdd(&cnt[d], 1);
    csr[slot] = s;
}

// --- tiled f32 GEMM: H[N,F] = X[N,K] @ W[K,F] (no bias here) ----------------
template <int K, int F>
__global__ __launch_bounds__(256) void k_gemm(const float* __restrict__ X,
                                              const float* __restrict__ W,
                                              float* __restrict__ H, int N) {
    constexpr int BK = 32;
    constexpr int TN = F / 16;               // cols per thread
    __shared__ float Xs[64][BK + 1];
    __shared__ float Ws[BK][F];
    int tid = threadIdx.x;
    int tr = tid >> 4;                        // 0..15 row group (4 rows each)
    int tc = tid & 15;                        // 0..15 col group (TN cols each)
    int row0 = blockIdx.x * 64;

    float acc[4][TN];
#pragma unroll
    for (int i = 0; i < 4; i++)
#pragma unroll
        for (int j = 0; j < TN; j++) acc[i][j] = 0.f;

    for (int k0 = 0; k0 < K; k0 += BK) {
        // stage X tile 64xBK
#pragma unroll
        for (int j = 0; j < 64 * BK; j += 256) {
            int idx = tid + j;
            int r = idx >> 5, c = idx & 31;
            int gr = row0 + r;
            Xs[r][c] = (gr < N) ? X[(size_t)gr * K + k0 + c] : 0.f;
        }
        // stage W tile BKxF
#pragma unroll
        for (int j = 0; j < BK * F; j += 256) {
            int idx = tid + j;
            int r = idx / F, c = idx % F;
            Ws[r][c] = W[(size_t)(k0 + r) * F + c];
        }
        __syncthreads();
#pragma unroll
        for (int k = 0; k < BK; k++) {
            float xv[4];
#pragma unroll
            for (int i = 0; i < 4; i++) xv[i] = Xs[tr * 4 + i][k];
            float wv[TN];
#pragma unroll
            for (int j = 0; j < TN; j++) wv[j] = Ws[k][tc * TN + j];
#pragma unroll
            for (int i = 0; i < 4; i++)
#pragma unroll
                for (int j = 0; j < TN; j++) acc[i][j] += xv[i] * wv[j];
        }
        __syncthreads();
    }
#pragma unroll
    for (int i = 0; i < 4; i++) {
        int gr = row0 + tr * 4 + i;
        if (gr < N) {
#pragma unroll
            for (int j = 0; j < TN; j++)
                H[(size_t)gr * F + tc * TN + j] = acc[i][j];
        }
    }
}

// --- per-dst-node aggregation: Y = act(dinv_d * sum(dinv_s * H[s]) + dinv_d^2*H[d] + b)
template <int F, bool RELU>
__global__ __launch_bounds__(256) void k_agg(const float* __restrict__ H,
                                             const int* __restrict__ offs,
                                             const int* __restrict__ csr,
                                             const float* __restrict__ dinv,
                                             const float* __restrict__ bias,
                                             float* __restrict__ Y, int N) {
    int node = blockIdx.x * 4 + (threadIdx.x >> 6);   // one wave per node
    int lane = threadIdx.x & 63;
    if (node >= N) return;
    constexpr int PF = F / 64;
    float acc[PF];
#pragma unroll
    for (int p = 0; p < PF; p++) acc[p] = 0.f;
    int o0 = offs[node], o1 = offs[node + 1];
    for (int e = o0; e < o1; e++) {
        int s = csr[e];                   // uniform across wave -> broadcast
        float w = dinv[s];
#pragma unroll
        for (int p = 0; p < PF; p++)
            acc[p] += w * H[(size_t)s * F + p * 64 + lane];
    }
    float di = dinv[node];
#pragma unroll
    for (int p = 0; p < PF; p++) {
        float v = di * acc[p] + di * di * H[(size_t)node * F + p * 64 + lane]
                  + bias[p * 64 + lane];
        if (RELU) v = (v > 0.f) ? v : 0.2f * v;
        Y[(size_t)node * F + p * 64 + lane] = v;
    }
}

extern "C" void kernel_launch(void* const* d_in, const int* in_sizes, int n_in,
                              void* d_out, int out_size, void* d_ws, size_t ws_size,
                              hipStream_t stream) {
    const float* x  = (const float*)d_in[0];
    const int*   ei = (const int*)d_in[1];
    const float* W1 = (const float*)d_in[2];
    const float* b1 = (const float*)d_in[3];
    const float* W2 = (const float*)d_in[4];
    const float* b2 = (const float*)d_in[5];
    const float* W3 = (const float*)d_in[6];
    const float* b3 = (const float*)d_in[7];

    const int N = in_sizes[0] / 512;
    const int E = in_sizes[1] / 2;
    const int nb = (N + 255) / 256;

    char* w = (char*)d_ws;
    auto take = [&](size_t bytes) -> char* {
        char* p = w;
        w += alignup(bytes, 256);
        return p;
    };
    int*   flag  = (int*)take(256);
    int*   deg   = (int*)take((size_t)N * 4);
    int*   cnt   = (int*)take((size_t)N * 4);
    int*   offs  = (int*)take((size_t)(N + 1) * 4);
    int*   bsums = (int*)take((size_t)nb * 4);
    int*   boffs = (int*)take((size_t)nb * 4);
    int*   csr   = (int*)take((size_t)E * 4);
    float* dinv  = (float*)take((size_t)N * 4);
    float* bufA  = (float*)take((size_t)N * 128 * 4);
    float* bufB  = (float*)take((size_t)N * 128 * 4);

    const int TB = 256;
    // preprocessing
    k_detect<<<1, 64, 0, stream>>>(ei, flag);
    k_zero2<<<(N + TB - 1) / TB, TB, 0, stream>>>(deg, cnt, N);
    k_deg<<<(E + TB - 1) / TB, TB, 0, stream>>>(ei, E, flag, deg);
    k_dinv<<<(N + TB - 1) / TB, TB, 0, stream>>>(deg, dinv, N);
    k_scan1<<<nb, 256, 0, stream>>>(deg, offs, bsums, N);
    k_scan2<<<1, 256, 0, stream>>>(bsums, boffs, nb);
    k_scan3<<<(N + TB - 1) / TB, TB, 0, stream>>>(offs, boffs, N, E);
    k_fill<<<(E + TB - 1) / TB, TB, 0, stream>>>(ei, E, flag, offs, cnt, csr);

    // layer 1: h1 = x @ W1 ; y1 = lrelu(agg(h1) + b1)
    k_gemm<512, 128><<<(N + 63) / 64, 256, 0, stream>>>(x, W1, bufA, N);
    k_agg<128, true><<<(N + 3) / 4, 256, 0, stream>>>(bufA, offs, csr, dinv, b1, bufB, N);
    // layer 2
    k_gemm<128, 64><<<(N + 63) / 64, 256, 0, stream>>>(bufB, W2, bufA, N);
    k_agg<64, true><<<(N + 3) / 4, 256, 0, stream>>>(bufA, offs, csr, dinv, b2, bufB, N);
    // layer 3 (no relu), write straight to output
    k_gemm<64, 64><<<(N + 63) / 64, 256, 0, stream>>>(bufB, W3, bufA, N);
    k_agg<64, false><<<(N + 3) / 4, 256, 0, stream>>>(bufA, offs, csr, dinv, b3,
                                                      (float*)d_out, N);
}

// Round 2
// 434.589 us; speedup vs baseline: 1.2468x; 1.2468x over previous
//
#include <hip/hip_runtime.h>

// ---------------------------------------------------------------------------
// GCN 3-layer forward on MI355X.
// detect edge layout -> deg -> dinv -> scan -> CSR fill -> [GEMM -> AGG] x3
// GEMM: A-fragments direct from global (row owned by one block, lane-broadcast),
//       W tile staged in LDS interleaved [k][2][64] -> conflict-free b128 reads.
// ---------------------------------------------------------------------------

static inline size_t alignup(size_t v, size_t a) { return (v + a - 1) & ~(a - 1); }

__device__ __forceinline__ float f4get(const float4& v, int j) {
    return j == 0 ? v.x : j == 1 ? v.y : j == 2 ? v.z : v.w;
}

// --- edge dtype detect: if input is int64, every odd 32-bit word is 0 -------
__global__ void k_detect(const int* __restrict__ ei, int* __restrict__ flag) {
    int v = ei[2 * threadIdx.x + 1];            // high word if int64
    unsigned long long b = __ballot(v != 0);
    if (threadIdx.x == 0) *flag = (b == 0ull) ? 1 : 0;   // 1 => int64 layout
}

__global__ void k_zero2(int* __restrict__ a, int* __restrict__ b, int n) {
    int i = blockIdx.x * blockDim.x + threadIdx.x;
    if (i < n) { a[i] = 0; b[i] = 0; }
}

__global__ void k_deg(const int* __restrict__ ei, int E,
                      const int* __restrict__ flag, int* __restrict__ deg) {
    int i = blockIdx.x * blockDim.x + threadIdx.x;
    if (i >= E) return;
    int is64 = *flag;
    int d = is64 ? ei[2 * (E + i)] : ei[E + i];
    atomicAdd(&deg[d], 1);
}

__global__ void k_dinv(const int* __restrict__ deg, float* __restrict__ dinv, int N) {
    int i = blockIdx.x * blockDim.x + threadIdx.x;
    if (i < N) dinv[i] = rsqrtf((float)deg[i] + 1.0f);
}

// --- 3-kernel exclusive scan over deg (256 elems/block) ---------------------
__global__ void k_scan1(const int* __restrict__ deg, int* __restrict__ offs,
                        int* __restrict__ bsums, int N) {
    __shared__ int s[256];
    int i = blockIdx.x * 256 + threadIdx.x;
    int v = (i < N) ? deg[i] : 0;
    s[threadIdx.x] = v;
    __syncthreads();
    for (int off = 1; off < 256; off <<= 1) {
        int t = (threadIdx.x >= off) ? s[threadIdx.x - off] : 0;
        __syncthreads();
        s[threadIdx.x] += t;
        __syncthreads();
    }
    if (i < N) offs[i] = s[threadIdx.x] - v;   // exclusive
    if (threadIdx.x == 255) bsums[blockIdx.x] = s[255];
}

__global__ void k_scan2(const int* __restrict__ bsums, int* __restrict__ boffs, int nb) {
    __shared__ int s[256];
    int i = threadIdx.x;
    int v = (i < nb) ? bsums[i] : 0;
    s[i] = v;
    __syncthreads();
    for (int off = 1; off < 256; off <<= 1) {
        int t = (i >= off) ? s[i - off] : 0;
        __syncthreads();
        s[i] += t;
        __syncthreads();
    }
    if (i < nb) boffs[i] = s[i] - v;
}

__global__ void k_scan3(int* __restrict__ offs, const int* __restrict__ boffs,
                        int N, int E) {
    int i = blockIdx.x * blockDim.x + threadIdx.x;
    if (i < N) offs[i] += boffs[i >> 8];
    if (i == 0) offs[N] = E;
}

__global__ void k_fill(const int* __restrict__ ei, int E,
                       const int* __restrict__ flag,
                       const int* __restrict__ offs, int* __restrict__ cnt,
                       int* __restrict__ csr) {
    int i = blockIdx.x * blockDim.x + threadIdx.x;
    if (i >= E) return;
    int is64 = *flag;
    int s = is64 ? ei[2 * i] : ei[i];
    int d = is64 ? ei[2 * (E + i)] : ei[E + i];
    int slot = offs[d] + atomicAdd(&cnt[d], 1);
    csr[slot] = s;
}

// --- tiled f32 GEMM: H[N,F] = X[N,K] @ W[K,F] --------------------------------
// 64-row x F-col block, 256 threads = 16(tr) x 16(tc); thread owns 4 rows x TN cols.
// A: direct global float4 (16-lane broadcast per row). B: LDS, conflict-free.
template <int K, int F>
__global__ __launch_bounds__(256) void k_gemm(const float* __restrict__ X,
                                              const float* __restrict__ Wm,
                                              float* __restrict__ H, int N) {
    constexpr int BK = 32;
    constexpr int TN = (F == 128) ? 8 : 4;
    constexpr int SLOTS = BK * F / 4;          // float4 slots in W tile
    __shared__ float Ws[BK * F];               // F=128: [k][2][64]; F=64: [k][64]

    const int tid = threadIdx.x;
    const int tr = tid >> 4;
    const int tc = tid & 15;
    const int row0 = blockIdx.x * 64;

    const float* xrow[4];
#pragma unroll
    for (int i = 0; i < 4; i++) {
        int gr = row0 + tr * 4 + i;
        xrow[i] = X + (size_t)((gr < N) ? gr : (N - 1)) * K;
    }

    float acc[4][TN];
#pragma unroll
    for (int i = 0; i < 4; i++)
#pragma unroll
        for (int j = 0; j < TN; j++) acc[i][j] = 0.f;

    for (int k0 = 0; k0 < K; k0 += BK) {
        // stage W tile (interleaved for F=128 so reads are contiguous 256B)
#pragma unroll
        for (int j = 0; j < SLOTS / 256; j++) {
            int f = tid + j * 256;
            float4 v;
            if (F == 128) {
                int k = f >> 5, h = (f >> 4) & 1, p = f & 15;
                v = *(const float4*)&Wm[(size_t)(k0 + k) * F + p * 8 + h * 4];
            } else {
                int k = f >> 4, c4 = f & 15;
                v = *(const float4*)&Wm[(size_t)(k0 + k) * F + c4 * 4];
            }
            *(float4*)&Ws[f * 4] = v;
        }
        __syncthreads();

        float4 a_cur[4], a_nxt[4];
#pragma unroll
        for (int i = 0; i < 4; i++) a_cur[i] = *(const float4*)&xrow[i][k0];

#pragma unroll
        for (int kc = 0; kc < BK / 4; kc++) {
            if (kc < BK / 4 - 1) {
#pragma unroll
                for (int i = 0; i < 4; i++)
                    a_nxt[i] = *(const float4*)&xrow[i][k0 + (kc + 1) * 4];
            }
#pragma unroll
            for (int j = 0; j < 4; j++) {
                const int k = kc * 4 + j;
                if (F == 128) {
                    float4 b0 = *(const float4*)&Ws[k * 128 + tc * 4];
                    float4 b1 = *(const float4*)&Ws[k * 128 + 64 + tc * 4];
#pragma unroll
                    for (int i = 0; i < 4; i++) {
                        float av = f4get(a_cur[i], j);
                        acc[i][0] += av * b0.x; acc[i][1] += av * b0.y;
                        acc[i][2] += av * b0.z; acc[i][3] += av * b0.w;
                        acc[i][4] += av * b1.x; acc[i][5] += av * b1.y;
                        acc[i][6] += av * b1.z; acc[i][7] += av * b1.w;
                    }
                } else {
                    float4 b0 = *(const float4*)&Ws[k * 64 + tc * 4];
#pragma unroll
                    for (int i = 0; i < 4; i++) {
                        float av = f4get(a_cur[i], j);
                        acc[i][0] += av * b0.x; acc[i][1] += av * b0.y;
                        acc[i][2] += av * b0.z; acc[i][3] += av * b0.w;
                    }
                }
            }
#pragma unroll
            for (int i = 0; i < 4; i++) a_cur[i] = a_nxt[i];
        }
        __syncthreads();
    }

#pragma unroll
    for (int i = 0; i < 4; i++) {
        int gr = row0 + tr * 4 + i;
        if (gr >= N) continue;
        float* hp = H + (size_t)gr * F + tc * TN;
        *(float4*)hp = make_float4(acc[i][0], acc[i][1], acc[i][2], acc[i][3]);
        if (F == 128)
            *(float4*)(hp + 4) = make_float4(acc[i][4], acc[i][5], acc[i][6], acc[i][7]);
    }
}

// --- aggregation, F=128: one wave per node, full row = one float2 wave read --
template <bool RELU>
__global__ __launch_bounds__(256) void k_agg128(const float* __restrict__ H,
                                                const int* __restrict__ offs,
                                                const int* __restrict__ csr,
                                                const float* __restrict__ dinv,
                                                const float* __restrict__ bias,
                                                float* __restrict__ Y, int N) {
    int node = blockIdx.x * 4 + (threadIdx.x >> 6);
    int lane = threadIdx.x & 63;
    if (node >= N) return;
    const float2* H2 = (const float2*)H;
    float ax = 0.f, ay = 0.f;
    int o0 = offs[node], o1 = offs[node + 1];
    int e = o0;
    for (; e + 2 <= o1; e += 2) {
        int s0 = csr[e], s1 = csr[e + 1];
        float w0 = dinv[s0], w1 = dinv[s1];
        float2 v0 = H2[(size_t)s0 * 64 + lane];
        float2 v1 = H2[(size_t)s1 * 64 + lane];
        ax += w0 * v0.x; ay += w0 * v0.y;
        ax += w1 * v1.x; ay += w1 * v1.y;
    }
    if (e < o1) {
        int s0 = csr[e];
        float w0 = dinv[s0];
        float2 v0 = H2[(size_t)s0 * 64 + lane];
        ax += w0 * v0.x; ay += w0 * v0.y;
    }
    float di = dinv[node];
    float2 hs = H2[(size_t)node * 64 + lane];
    float2 bv = ((const float2*)bias)[lane];
    float vx = di * ax + di * di * hs.x + bv.x;
    float vy = di * ay + di * di * hs.y + bv.y;
    if (RELU) { vx = vx > 0.f ? vx : 0.2f * vx; vy = vy > 0.f ? vy : 0.2f * vy; }
    ((float2*)Y)[(size_t)node * 64 + lane] = make_float2(vx, vy);
}

// --- aggregation, F=64: one wave per node, row = one b32 wave read -----------
template <bool RELU>
__global__ __launch_bounds__(256) void k_agg64(const float* __restrict__ H,
                                               const int* __restrict__ offs,
                                               const int* __restrict__ csr,
                                               const float* __restrict__ dinv,
                                               const float* __restrict__ bias,
                                               float* __restrict__ Y, int N) {
    int node = blockIdx.x * 4 + (threadIdx.x >> 6);
    int lane = threadIdx.x & 63;
    if (node >= N) return;
    float acc = 0.f;
    int o0 = offs[node], o1 = offs[node + 1];
    int e = o0;
    for (; e + 2 <= o1; e += 2) {
        int s0 = csr[e], s1 = csr[e + 1];
        float w0 = dinv[s0], w1 = dinv[s1];
        acc += w0 * H[(size_t)s0 * 64 + lane];
        acc += w1 * H[(size_t)s1 * 64 + lane];
    }
    if (e < o1) {
        int s0 = csr[e];
        acc += dinv[s0] * H[(size_t)s0 * 64 + lane];
    }
    float di = dinv[node];
    float v = di * acc + di * di * H[(size_t)node * 64 + lane] + bias[lane];
    if (RELU) v = v > 0.f ? v : 0.2f * v;
    Y[(size_t)node * 64 + lane] = v;
}

extern "C" void kernel_launch(void* const* d_in, const int* in_sizes, int n_in,
                              void* d_out, int out_size, void* d_ws, size_t ws_size,
                              hipStream_t stream) {
    const float* x  = (const float*)d_in[0];
    const int*   ei = (const int*)d_in[1];
    const float* W1 = (const float*)d_in[2];
    const float* b1 = (const float*)d_in[3];
    const float* W2 = (const float*)d_in[4];
    const float* b2 = (const float*)d_in[5];
    const float* W3 = (const float*)d_in[6];
    const float* b3 = (const float*)d_in[7];

    const int N = in_sizes[0] / 512;
    const int E = in_sizes[1] / 2;
    const int nb = (N + 255) / 256;

    char* w = (char*)d_ws;
    auto take = [&](size_t bytes) -> char* {
        char* p = w;
        w += alignup(bytes, 256);
        return p;
    };
    int*   flag  = (int*)take(256);
    int*   deg   = (int*)take((size_t)N * 4);
    int*   cnt   = (int*)take((size_t)N * 4);
    int*   offs  = (int*)take((size_t)(N + 1) * 4);
    int*   bsums = (int*)take((size_t)nb * 4);
    int*   boffs = (int*)take((size_t)nb * 4);
    int*   csr   = (int*)take((size_t)E * 4);
    float* dinv  = (float*)take((size_t)N * 4);
    float* bufA  = (float*)take((size_t)N * 128 * 4);
    float* bufB  = (float*)take((size_t)N * 128 * 4);

    const int TB = 256;
    // preprocessing
    k_detect<<<1, 64, 0, stream>>>(ei, flag);
    k_zero2<<<(N + TB - 1) / TB, TB, 0, stream>>>(deg, cnt, N);
    k_deg<<<(E + TB - 1) / TB, TB, 0, stream>>>(ei, E, flag, deg);
    k_dinv<<<(N + TB - 1) / TB, TB, 0, stream>>>(deg, dinv, N);
    k_scan1<<<nb, 256, 0, stream>>>(deg, offs, bsums, N);
    k_scan2<<<1, 256, 0, stream>>>(bsums, boffs, nb);
    k_scan3<<<(N + TB - 1) / TB, TB, 0, stream>>>(offs, boffs, N, E);
    k_fill<<<(E + TB - 1) / TB, TB, 0, stream>>>(ei, E, flag, offs, cnt, csr);

    const int gemm_grid = (N + 63) / 64;
    const int agg_grid = (N + 3) / 4;
    // layer 1
    k_gemm<512, 128><<<gemm_grid, 256, 0, stream>>>(x, W1, bufA, N);
    k_agg128<true><<<agg_grid, 256, 0, stream>>>(bufA, offs, csr, dinv, b1, bufB, N);
    // layer 2
    k_gemm<128, 64><<<gemm_grid, 256, 0, stream>>>(bufB, W2, bufA, N);
    k_agg64<true><<<agg_grid, 256, 0, stream>>>(bufA, offs, csr, dinv, b2, bufB, N);
    // layer 3 (no relu), write straight to output
    k_gemm<64, 64><<<gemm_grid, 256, 0, stream>>>(bufB, W3, bufA, N);
    k_agg64<false><<<agg_grid, 256, 0, stream>>>(bufA, offs, csr, dinv, b3,
                                                 (float*)d_out, N);
}

// Round 3
// 342.212 us; speedup vs baseline: 1.5833x; 1.2699x over previous
//
#include <hip/hip_runtime.h>

// ---------------------------------------------------------------------------
// GCN 3-layer forward on MI355X.
// detect edge layout -> deg -> dinv -> scan -> CSR fill -> W-split x3
//   -> [MFMA GEMM (bf16x3 split emulation of f32) -> AGG] x3
// GEMM: no LDS, no barriers. B = pre-split bf16 hi/lo in fragment order
// (coalesced 16B global loads, L2-resident). A = f32 global, split in-reg.
// ---------------------------------------------------------------------------

typedef __attribute__((ext_vector_type(8))) short bf16x8;
typedef __attribute__((ext_vector_type(4))) float f32x4;
typedef unsigned short u16;
typedef unsigned int u32;

static inline size_t alignup(size_t v, size_t a) { return (v + a - 1) & ~(a - 1); }

// pack top-16 bits of two f32 bit patterns into one u32 (lo half from b0)
__device__ __forceinline__ u32 pack_hi16(u32 b0, u32 b1) {
    return __builtin_amdgcn_perm(b1, b0, 0x07060302u);
}

// --- edge dtype detect: if input is int64, every odd 32-bit word is 0 -------
__global__ void k_detect(const int* __restrict__ ei, int* __restrict__ flag) {
    int v = ei[2 * threadIdx.x + 1];
    unsigned long long b = __ballot(v != 0);
    if (threadIdx.x == 0) *flag = (b == 0ull) ? 1 : 0;   // 1 => int64 layout
}

__global__ void k_zero2(int* __restrict__ a, int* __restrict__ b, int n) {
    int i = blockIdx.x * blockDim.x + threadIdx.x;
    if (i < n) { a[i] = 0; b[i] = 0; }
}

__global__ void k_deg(const int* __restrict__ ei, int E,
                      const int* __restrict__ flag, int* __restrict__ deg) {
    int i = blockIdx.x * blockDim.x + threadIdx.x;
    if (i >= E) return;
    int is64 = *flag;
    int d = is64 ? ei[2 * (E + i)] : ei[E + i];
    atomicAdd(&deg[d], 1);
}

__global__ void k_dinv(const int* __restrict__ deg, float* __restrict__ dinv, int N) {
    int i = blockIdx.x * blockDim.x + threadIdx.x;
    if (i < N) dinv[i] = rsqrtf((float)deg[i] + 1.0f);
}

// --- 3-kernel exclusive scan over deg (256 elems/block) ---------------------
__global__ void k_scan1(const int* __restrict__ deg, int* __restrict__ offs,
                        int* __restrict__ bsums, int N) {
    __shared__ int s[256];
    int i = blockIdx.x * 256 + threadIdx.x;
    int v = (i < N) ? deg[i] : 0;
    s[threadIdx.x] = v;
    __syncthreads();
    for (int off = 1; off < 256; off <<= 1) {
        int t = (threadIdx.x >= off) ? s[threadIdx.x - off] : 0;
        __syncthreads();
        s[threadIdx.x] += t;
        __syncthreads();
    }
    if (i < N) offs[i] = s[threadIdx.x] - v;   // exclusive
    if (threadIdx.x == 255) bsums[blockIdx.x] = s[255];
}

__global__ void k_scan2(const int* __restrict__ bsums, int* __restrict__ boffs, int nb) {
    __shared__ int s[256];
    int i = threadIdx.x;
    int v = (i < nb) ? bsums[i] : 0;
    s[i] = v;
    __syncthreads();
    for (int off = 1; off < 256; off <<= 1) {
        int t = (i >= off) ? s[i - off] : 0;
        __syncthreads();
        s[i] += t;
        __syncthreads();
    }
    if (i < nb) boffs[i] = s[i] - v;
}

__global__ void k_scan3(int* __restrict__ offs, const int* __restrict__ boffs,
                        int N, int E) {
    int i = blockIdx.x * blockDim.x + threadIdx.x;
    if (i < N) offs[i] += boffs[i >> 8];
    if (i == 0) offs[N] = E;
}

__global__ void k_fill(const int* __restrict__ ei, int E,
                       const int* __restrict__ flag,
                       const int* __restrict__ offs, int* __restrict__ cnt,
                       int* __restrict__ csr) {
    int i = blockIdx.x * blockDim.x + threadIdx.x;
    if (i >= E) return;
    int is64 = *flag;
    int s = is64 ? ei[2 * i] : ei[i];
    int d = is64 ? ei[2 * (E + i)] : ei[E + i];
    int slot = offs[d] + atomicAdd(&cnt[d], 1);
    csr[slot] = s;
}

// --- W pre-split into fragment-ordered bf16 hi/lo ----------------------------
// slot s = ((t*4+g)*F + c) holds W[t*32+g*8+j][c], j=0..7, as 8 bf16 (16 B).
template <int K, int F>
__global__ void k_splitW(const float* __restrict__ W, u16* __restrict__ Wh,
                         u16* __restrict__ Wl) {
    int s = blockIdx.x * 256 + threadIdx.x;
    if (s >= K * F / 8) return;
    int c = s % F;
    int kb = (s / F) * 8;
    union { u32 u[4]; bf16x8 v; } hi, lo;
#pragma unroll
    for (int p = 0; p < 4; p++) {
        float x0 = W[(size_t)(kb + 2 * p) * F + c];
        float x1 = W[(size_t)(kb + 2 * p + 1) * F + c];
        u32 b0 = __float_as_uint(x0), b1 = __float_as_uint(x1);
        float l0 = x0 - __uint_as_float(b0 & 0xFFFF0000u);
        float l1 = x1 - __uint_as_float(b1 & 0xFFFF0000u);
        hi.u[p] = pack_hi16(b0, b1);
        lo.u[p] = pack_hi16(__float_as_uint(l0), __float_as_uint(l1));
    }
    *(bf16x8*)(Wh + (size_t)s * 8) = hi.v;
    *(bf16x8*)(Wl + (size_t)s * 8) = lo.v;
}

// --- MFMA GEMM: H[N,F] = X[N,K] @ W[K,F], bf16x3 split emulation -------------
// 256 thr = 4 waves; block = 128 rows x F cols.
// F=128: wave tile 64x64 (MF=4); F=64: wave tile 32x64 (MF=2). NF=4.
template <int K, int F>
__global__ __launch_bounds__(256) void k_gemm_mfma(const float* __restrict__ X,
        const u16* __restrict__ Wh, const u16* __restrict__ Wl,
        float* __restrict__ H, int N) {
    constexpr int WNW = F / 64;
    constexpr int MF = 2 * WNW;
    constexpr int NF = 4;
    const int tid = threadIdx.x;
    const int w = tid >> 6, lane = tid & 63;
    const int wm = w / WNW, wn = w % WNW;
    const int lg = lane >> 4, li = lane & 15;
    const int row0 = blockIdx.x * 128 + wm * (MF * 16);
    const int colbase = wn * 64;

    const float* xrow[MF];
#pragma unroll
    for (int m = 0; m < MF; m++) {
        int r = row0 + m * 16 + li;
        xrow[m] = X + (size_t)(r < N ? r : N - 1) * K;
    }

    f32x4 acc[MF][NF];
#pragma unroll
    for (int m = 0; m < MF; m++)
#pragma unroll
        for (int n = 0; n < NF; n++) acc[m][n] = (f32x4){0.f, 0.f, 0.f, 0.f};

#pragma unroll 2
    for (int t = 0; t < K / 32; t++) {
        // B fragments: direct coalesced 16B loads (L2-resident)
        bf16x8 bh[NF], bl[NF];
        size_t slot0 = (size_t)(t * 4 + lg) * F + colbase + li;
#pragma unroll
        for (int n = 0; n < NF; n++) {
            bh[n] = *(const bf16x8*)(Wh + (slot0 + n * 16) * 8);
            bl[n] = *(const bf16x8*)(Wl + (slot0 + n * 16) * 8);
        }
        // A fragments: 8 consecutive f32 -> hi/lo bf16x8 (in-register split)
        bf16x8 ah[MF], al[MF];
#pragma unroll
        for (int m = 0; m < MF; m++) {
            const float* p = xrow[m] + t * 32 + lg * 8;
            float4 a0 = *(const float4*)p;
            float4 a1 = *(const float4*)(p + 4);
            float x[8] = {a0.x, a0.y, a0.z, a0.w, a1.x, a1.y, a1.z, a1.w};
            union { u32 u[4]; bf16x8 v; } hi, lo;
#pragma unroll
            for (int q = 0; q < 4; q++) {
                u32 b0 = __float_as_uint(x[2 * q]);
                u32 b1 = __float_as_uint(x[2 * q + 1]);
                float l0 = x[2 * q]     - __uint_as_float(b0 & 0xFFFF0000u);
                float l1 = x[2 * q + 1] - __uint_as_float(b1 & 0xFFFF0000u);
                hi.u[q] = pack_hi16(b0, b1);
                lo.u[q] = pack_hi16(__float_as_uint(l0), __float_as_uint(l1));
            }
            ah[m] = hi.v;
            al[m] = lo.v;
        }
        // 3-product accumulation: xh*wh + xh*wl + xl*wh
#pragma unroll
        for (int m = 0; m < MF; m++)
#pragma unroll
            for (int n = 0; n < NF; n++) {
                acc[m][n] = __builtin_amdgcn_mfma_f32_16x16x32_bf16(ah[m], bh[n], acc[m][n], 0, 0, 0);
                acc[m][n] = __builtin_amdgcn_mfma_f32_16x16x32_bf16(ah[m], bl[n], acc[m][n], 0, 0, 0);
                acc[m][n] = __builtin_amdgcn_mfma_f32_16x16x32_bf16(al[m], bh[n], acc[m][n], 0, 0, 0);
            }
    }

    // C/D layout: col = lane&15, row = (lane>>4)*4 + reg (m89-verified)
#pragma unroll
    for (int m = 0; m < MF; m++) {
        int rb = row0 + m * 16 + lg * 4;
#pragma unroll
        for (int n = 0; n < NF; n++) {
            int col = colbase + n * 16 + li;
#pragma unroll
            for (int r = 0; r < 4; r++) {
                int gr = rb + r;
                if (gr < N) H[(size_t)gr * F + col] = acc[m][n][r];
            }
        }
    }
}

// --- aggregation, F=128: one wave per node, full row = one float2 wave read --
template <bool RELU>
__global__ __launch_bounds__(256) void k_agg128(const float* __restrict__ H,
                                                const int* __restrict__ offs,
                                                const int* __restrict__ csr,
                                                const float* __restrict__ dinv,
                                                const float* __restrict__ bias,
                                                float* __restrict__ Y, int N) {
    int node = blockIdx.x * 4 + (threadIdx.x >> 6);
    int lane = threadIdx.x & 63;
    if (node >= N) return;
    const float2* H2 = (const float2*)H;
    float ax = 0.f, ay = 0.f;
    int o0 = offs[node], o1 = offs[node + 1];
    int e = o0;
    for (; e + 2 <= o1; e += 2) {
        int s0 = csr[e], s1 = csr[e + 1];
        float w0 = dinv[s0], w1 = dinv[s1];
        float2 v0 = H2[(size_t)s0 * 64 + lane];
        float2 v1 = H2[(size_t)s1 * 64 + lane];
        ax += w0 * v0.x; ay += w0 * v0.y;
        ax += w1 * v1.x; ay += w1 * v1.y;
    }
    if (e < o1) {
        int s0 = csr[e];
        float w0 = dinv[s0];
        float2 v0 = H2[(size_t)s0 * 64 + lane];
        ax += w0 * v0.x; ay += w0 * v0.y;
    }
    float di = dinv[node];
    float2 hs = H2[(size_t)node * 64 + lane];
    float2 bv = ((const float2*)bias)[lane];
    float vx = di * ax + di * di * hs.x + bv.x;
    float vy = di * ay + di * di * hs.y + bv.y;
    if (RELU) { vx = vx > 0.f ? vx : 0.2f * vx; vy = vy > 0.f ? vy : 0.2f * vy; }
    ((float2*)Y)[(size_t)node * 64 + lane] = make_float2(vx, vy);
}

// --- aggregation, F=64: one wave per node, row = one b32 wave read -----------
template <bool RELU>
__global__ __launch_bounds__(256) void k_agg64(const float* __restrict__ H,
                                               const int* __restrict__ offs,
                                               const int* __restrict__ csr,
                                               const float* __restrict__ dinv,
                                               const float* __restrict__ bias,
                                               float* __restrict__ Y, int N) {
    int node = blockIdx.x * 4 + (threadIdx.x >> 6);
    int lane = threadIdx.x & 63;
    if (node >= N) return;
    float acc = 0.f;
    int o0 = offs[node], o1 = offs[node + 1];
    int e = o0;
    for (; e + 2 <= o1; e += 2) {
        int s0 = csr[e], s1 = csr[e + 1];
        float w0 = dinv[s0], w1 = dinv[s1];
        acc += w0 * H[(size_t)s0 * 64 + lane];
        acc += w1 * H[(size_t)s1 * 64 + lane];
    }
    if (e < o1) {
        int s0 = csr[e];
        acc += dinv[s0] * H[(size_t)s0 * 64 + lane];
    }
    float di = dinv[node];
    float v = di * acc + di * di * H[(size_t)node * 64 + lane] + bias[lane];
    if (RELU) v = v > 0.f ? v : 0.2f * v;
    Y[(size_t)node * 64 + lane] = v;
}

extern "C" void kernel_launch(void* const* d_in, const int* in_sizes, int n_in,
                              void* d_out, int out_size, void* d_ws, size_t ws_size,
                              hipStream_t stream) {
    const float* x  = (const float*)d_in[0];
    const int*   ei = (const int*)d_in[1];
    const float* W1 = (const float*)d_in[2];
    const float* b1 = (const float*)d_in[3];
    const float* W2 = (const float*)d_in[4];
    const float* b2 = (const float*)d_in[5];
    const float* W3 = (const float*)d_in[6];
    const float* b3 = (const float*)d_in[7];

    const int N = in_sizes[0] / 512;
    const int E = in_sizes[1] / 2;
    const int nb = (N + 255) / 256;

    char* w = (char*)d_ws;
    auto take = [&](size_t bytes) -> char* {
        char* p = w;
        w += alignup(bytes, 256);
        return p;
    };
    int*   flag  = (int*)take(256);
    int*   deg   = (int*)take((size_t)N * 4);
    int*   cnt   = (int*)take((size_t)N * 4);
    int*   offs  = (int*)take((size_t)(N + 1) * 4);
    int*   bsums = (int*)take((size_t)nb * 4);
    int*   boffs = (int*)take((size_t)nb * 4);
    int*   csr   = (int*)take((size_t)E * 4);
    float* dinv  = (float*)take((size_t)N * 4);
    float* bufA  = (float*)take((size_t)N * 128 * 4);
    float* bufB  = (float*)take((size_t)N * 128 * 4);
    u16*   w1h   = (u16*)take((size_t)512 * 128 * 2);
    u16*   w1l   = (u16*)take((size_t)512 * 128 * 2);
    u16*   w2h   = (u16*)take((size_t)128 * 64 * 2);
    u16*   w2l   = (u16*)take((size_t)128 * 64 * 2);
    u16*   w3h   = (u16*)take((size_t)64 * 64 * 2);
    u16*   w3l   = (u16*)take((size_t)64 * 64 * 2);

    const int TB = 256;
    // preprocessing
    k_detect<<<1, 64, 0, stream>>>(ei, flag);
    k_zero2<<<(N + TB - 1) / TB, TB, 0, stream>>>(deg, cnt, N);
    k_deg<<<(E + TB - 1) / TB, TB, 0, stream>>>(ei, E, flag, deg);
    k_dinv<<<(N + TB - 1) / TB, TB, 0, stream>>>(deg, dinv, N);
    k_scan1<<<nb, 256, 0, stream>>>(deg, offs, bsums, N);
    k_scan2<<<1, 256, 0, stream>>>(bsums, boffs, nb);
    k_scan3<<<(N + TB - 1) / TB, TB, 0, stream>>>(offs, boffs, N, E);
    k_fill<<<(E + TB - 1) / TB, TB, 0, stream>>>(ei, E, flag, offs, cnt, csr);
    // W splits
    k_splitW<512, 128><<<(512 * 128 / 8 + 255) / 256, 256, 0, stream>>>(W1, w1h, w1l);
    k_splitW<128, 64><<<(128 * 64 / 8 + 255) / 256, 256, 0, stream>>>(W2, w2h, w2l);
    k_splitW<64, 64><<<(64 * 64 / 8 + 255) / 256, 256, 0, stream>>>(W3, w3h, w3l);

    const int gemm_grid = (N + 127) / 128;
    const int agg_grid = (N + 3) / 4;
    // layer 1
    k_gemm_mfma<512, 128><<<gemm_grid, 256, 0, stream>>>(x, w1h, w1l, bufA, N);
    k_agg128<true><<<agg_grid, 256, 0, stream>>>(bufA, offs, csr, dinv, b1, bufB, N);
    // layer 2
    k_gemm_mfma<128, 64><<<gemm_grid, 256, 0, stream>>>(bufB, w2h, w2l, bufA, N);
    k_agg64<true><<<agg_grid, 256, 0, stream>>>(bufA, offs, csr, dinv, b2, bufB, N);
    // layer 3 (no relu), write straight to output
    k_gemm_mfma<64, 64><<<gemm_grid, 256, 0, stream>>>(bufB, w3h, w3l, bufA, N);
    k_agg64<false><<<agg_grid, 256, 0, stream>>>(bufA, offs, csr, dinv, b3,
                                                 (float*)d_out, N);
}

// Round 4
// 278.117 us; speedup vs baseline: 1.9482x; 1.2305x over previous
//
#include <hip/hip_runtime.h>
#include <hip/hip_fp16.h>

// ---------------------------------------------------------------------------
// GCN 3-layer forward on MI355X.
// detect edge layout -> deg -> dinv -> scan -> CSR fill -> W-split x3
//   -> [MFMA GEMM (bf16x3 split of f32) + dinv-scaled fp16 epilogue -> AGG] x3
// GEMM: no LDS/barriers; B pre-split bf16 hi/lo fragment-ordered (L2-resident),
//       A f32 global split in-register. Epilogue writes H' = dinv[row]*h, fp16.
// AGG:  per-dst wave gather of fp16 H' rows, 4-edge unroll, f32 accumulate.
//       y = dinv_d*(sum H'[s] + H'[d]) + b  (dinv folded at both ends).
// ---------------------------------------------------------------------------

typedef __attribute__((ext_vector_type(8))) short bf16x8;
typedef __attribute__((ext_vector_type(4))) float f32x4;
typedef unsigned short u16;
typedef unsigned int u32;

static inline size_t alignup(size_t v, size_t a) { return (v + a - 1) & ~(a - 1); }

// pack top-16 bits of two f32 bit patterns into one u32 (lo half from b0)
__device__ __forceinline__ u32 pack_hi16(u32 b0, u32 b1) {
    return __builtin_amdgcn_perm(b1, b0, 0x07060302u);
}

// --- edge dtype detect: if input is int64, every odd 32-bit word is 0 -------
__global__ void k_detect(const int* __restrict__ ei, int* __restrict__ flag) {
    int v = ei[2 * threadIdx.x + 1];
    unsigned long long b = __ballot(v != 0);
    if (threadIdx.x == 0) *flag = (b == 0ull) ? 1 : 0;   // 1 => int64 layout
}

__global__ void k_zero2(int* __restrict__ a, int* __restrict__ b, int n) {
    int i = blockIdx.x * blockDim.x + threadIdx.x;
    if (i < n) { a[i] = 0; b[i] = 0; }
}

__global__ void k_deg(const int* __restrict__ ei, int E,
                      const int* __restrict__ flag, int* __restrict__ deg) {
    int i = blockIdx.x * blockDim.x + threadIdx.x;
    if (i >= E) return;
    int is64 = *flag;
    int d = is64 ? ei[2 * (E + i)] : ei[E + i];
    atomicAdd(&deg[d], 1);
}

__global__ void k_dinv(const int* __restrict__ deg, float* __restrict__ dinv, int N) {
    int i = blockIdx.x * blockDim.x + threadIdx.x;
    if (i < N) dinv[i] = rsqrtf((float)deg[i] + 1.0f);
}

// --- 3-kernel exclusive scan over deg (256 elems/block) ---------------------
__global__ void k_scan1(const int* __restrict__ deg, int* __restrict__ offs,
                        int* __restrict__ bsums, int N) {
    __shared__ int s[256];
    int i = blockIdx.x * 256 + threadIdx.x;
    int v = (i < N) ? deg[i] : 0;
    s[threadIdx.x] = v;
    __syncthreads();
    for (int off = 1; off < 256; off <<= 1) {
        int t = (threadIdx.x >= off) ? s[threadIdx.x - off] : 0;
        __syncthreads();
        s[threadIdx.x] += t;
        __syncthreads();
    }
    if (i < N) offs[i] = s[threadIdx.x] - v;   // exclusive
    if (threadIdx.x == 255) bsums[blockIdx.x] = s[255];
}

__global__ void k_scan2(const int* __restrict__ bsums, int* __restrict__ boffs, int nb) {
    __shared__ int s[256];
    int i = threadIdx.x;
    int v = (i < nb) ? bsums[i] : 0;
    s[i] = v;
    __syncthreads();
    for (int off = 1; off < 256; off <<= 1) {
        int t = (i >= off) ? s[i - off] : 0;
        __syncthreads();
        s[i] += t;
        __syncthreads();
    }
    if (i < nb) boffs[i] = s[i] - v;
}

__global__ void k_scan3(int* __restrict__ offs, const int* __restrict__ boffs,
                        int N, int E) {
    int i = blockIdx.x * blockDim.x + threadIdx.x;
    if (i < N) offs[i] += boffs[i >> 8];
    if (i == 0) offs[N] = E;
}

__global__ void k_fill(const int* __restrict__ ei, int E,
                       const int* __restrict__ flag,
                       const int* __restrict__ offs, int* __restrict__ cnt,
                       int* __restrict__ csr) {
    int i = blockIdx.x * blockDim.x + threadIdx.x;
    if (i >= E) return;
    int is64 = *flag;
    int s = is64 ? ei[2 * i] : ei[i];
    int d = is64 ? ei[2 * (E + i)] : ei[E + i];
    int slot = offs[d] + atomicAdd(&cnt[d], 1);
    csr[slot] = s;
}

// --- W pre-split into fragment-ordered bf16 hi/lo ----------------------------
// slot s = ((t*4+g)*F + c) holds W[t*32+g*8+j][c], j=0..7, as 8 bf16 (16 B).
template <int K, int F>
__global__ void k_splitW(const float* __restrict__ W, u16* __restrict__ Wh,
                         u16* __restrict__ Wl) {
    int s = blockIdx.x * 256 + threadIdx.x;
    if (s >= K * F / 8) return;
    int c = s % F;
    int kb = (s / F) * 8;
    union { u32 u[4]; bf16x8 v; } hi, lo;
#pragma unroll
    for (int p = 0; p < 4; p++) {
        float x0 = W[(size_t)(kb + 2 * p) * F + c];
        float x1 = W[(size_t)(kb + 2 * p + 1) * F + c];
        u32 b0 = __float_as_uint(x0), b1 = __float_as_uint(x1);
        float l0 = x0 - __uint_as_float(b0 & 0xFFFF0000u);
        float l1 = x1 - __uint_as_float(b1 & 0xFFFF0000u);
        hi.u[p] = pack_hi16(b0, b1);
        lo.u[p] = pack_hi16(__float_as_uint(l0), __float_as_uint(l1));
    }
    *(bf16x8*)(Wh + (size_t)s * 8) = hi.v;
    *(bf16x8*)(Wl + (size_t)s * 8) = lo.v;
}

// --- MFMA GEMM: H'[N,F] = dinv_row * (X[N,K] @ W[K,F]), fp16 out -------------
// 256 thr = 4 waves; block = 128 rows x F cols.
// F=128: wave tile 64x64 (MF=4); F=64: wave tile 32x64 (MF=2). NF=4.
template <int K, int F>
__global__ __launch_bounds__(256) void k_gemm_mfma(const float* __restrict__ X,
        const u16* __restrict__ Wh, const u16* __restrict__ Wl,
        const float* __restrict__ dinv, __half* __restrict__ Hh, int N) {
    constexpr int WNW = F / 64;
    constexpr int MF = 2 * WNW;
    constexpr int NF = 4;
    const int tid = threadIdx.x;
    const int w = tid >> 6, lane = tid & 63;
    const int wm = w / WNW, wn = w % WNW;
    const int lg = lane >> 4, li = lane & 15;
    const int row0 = blockIdx.x * 128 + wm * (MF * 16);
    const int colbase = wn * 64;

    const float* xrow[MF];
#pragma unroll
    for (int m = 0; m < MF; m++) {
        int r = row0 + m * 16 + li;
        xrow[m] = X + (size_t)(r < N ? r : N - 1) * K;
    }

    f32x4 acc[MF][NF];
#pragma unroll
    for (int m = 0; m < MF; m++)
#pragma unroll
        for (int n = 0; n < NF; n++) acc[m][n] = (f32x4){0.f, 0.f, 0.f, 0.f};

#pragma unroll 2
    for (int t = 0; t < K / 32; t++) {
        // B fragments: direct coalesced 16B loads (L2-resident)
        bf16x8 bh[NF], bl[NF];
        size_t slot0 = (size_t)(t * 4 + lg) * F + colbase + li;
#pragma unroll
        for (int n = 0; n < NF; n++) {
            bh[n] = *(const bf16x8*)(Wh + (slot0 + n * 16) * 8);
            bl[n] = *(const bf16x8*)(Wl + (slot0 + n * 16) * 8);
        }
        // A fragments: 8 consecutive f32 -> hi/lo bf16x8 (in-register split)
        bf16x8 ah[MF], al[MF];
#pragma unroll
        for (int m = 0; m < MF; m++) {
            const float* p = xrow[m] + t * 32 + lg * 8;
            float4 a0 = *(const float4*)p;
            float4 a1 = *(const float4*)(p + 4);
            float x[8] = {a0.x, a0.y, a0.z, a0.w, a1.x, a1.y, a1.z, a1.w};
            union { u32 u[4]; bf16x8 v; } hi, lo;
#pragma unroll
            for (int q = 0; q < 4; q++) {
                u32 b0 = __float_as_uint(x[2 * q]);
                u32 b1 = __float_as_uint(x[2 * q + 1]);
                float l0 = x[2 * q]     - __uint_as_float(b0 & 0xFFFF0000u);
                float l1 = x[2 * q + 1] - __uint_as_float(b1 & 0xFFFF0000u);
                hi.u[q] = pack_hi16(b0, b1);
                lo.u[q] = pack_hi16(__float_as_uint(l0), __float_as_uint(l1));
            }
            ah[m] = hi.v;
            al[m] = lo.v;
        }
        // 3-product accumulation: xh*wh + xh*wl + xl*wh
#pragma unroll
        for (int m = 0; m < MF; m++)
#pragma unroll
            for (int n = 0; n < NF; n++) {
                acc[m][n] = __builtin_amdgcn_mfma_f32_16x16x32_bf16(ah[m], bh[n], acc[m][n], 0, 0, 0);
                acc[m][n] = __builtin_amdgcn_mfma_f32_16x16x32_bf16(ah[m], bl[n], acc[m][n], 0, 0, 0);
                acc[m][n] = __builtin_amdgcn_mfma_f32_16x16x32_bf16(al[m], bh[n], acc[m][n], 0, 0, 0);
            }
    }

    // C/D layout: col = lane&15, row = (lane>>4)*4 + reg (m89-verified)
    // Epilogue folds dinv[row] and converts to fp16.
#pragma unroll
    for (int m = 0; m < MF; m++) {
        int rb = row0 + m * 16 + lg * 4;
#pragma unroll
        for (int r = 0; r < 4; r++) {
            int gr = rb + r;
            if (gr >= N) continue;
            float di = dinv[gr];
#pragma unroll
            for (int n = 0; n < NF; n++) {
                int col = colbase + n * 16 + li;
                Hh[(size_t)gr * F + col] = __float2half(acc[m][n][r] * di);
            }
        }
    }
}

// --- aggregation, F=128, fp16 H' in, f32 out ---------------------------------
// y = act(dinv_d * (sum_s H'[s] + H'[d]) + b); one wave per node; 4-edge unroll.
template <bool RELU>
__global__ __launch_bounds__(256) void k_agg128(const __half* __restrict__ Hh,
                                                const int* __restrict__ offs,
                                                const int* __restrict__ csr,
                                                const float* __restrict__ dinv,
                                                const float* __restrict__ bias,
                                                float* __restrict__ Y, int N) {
    int node = blockIdx.x * 4 + (threadIdx.x >> 6);
    int lane = threadIdx.x & 63;
    if (node >= N) return;
    const __half2* H2 = (const __half2*)Hh;   // row = 64 half2
    float ax = 0.f, ay = 0.f;
    int o0 = offs[node], o1 = offs[node + 1];
    int e = o0;
    for (; e + 4 <= o1; e += 4) {
        int s0 = csr[e], s1 = csr[e + 1], s2 = csr[e + 2], s3 = csr[e + 3];
        __half2 v0 = H2[(size_t)s0 * 64 + lane];
        __half2 v1 = H2[(size_t)s1 * 64 + lane];
        __half2 v2 = H2[(size_t)s2 * 64 + lane];
        __half2 v3 = H2[(size_t)s3 * 64 + lane];
        float2 f0 = __half22float2(v0), f1 = __half22float2(v1);
        float2 f2 = __half22float2(v2), f3 = __half22float2(v3);
        ax += (f0.x + f1.x) + (f2.x + f3.x);
        ay += (f0.y + f1.y) + (f2.y + f3.y);
    }
    for (; e < o1; ++e) {
        float2 f0 = __half22float2(H2[(size_t)csr[e] * 64 + lane]);
        ax += f0.x; ay += f0.y;
    }
    float2 fs = __half22float2(H2[(size_t)node * 64 + lane]);
    float di = dinv[node];
    float2 bv = ((const float2*)bias)[lane];
    float vx = di * (ax + fs.x) + bv.x;
    float vy = di * (ay + fs.y) + bv.y;
    if (RELU) { vx = vx > 0.f ? vx : 0.2f * vx; vy = vy > 0.f ? vy : 0.2f * vy; }
    ((float2*)Y)[(size_t)node * 64 + lane] = make_float2(vx, vy);
}

// --- aggregation, F=64, fp16 H' in, f32 out ----------------------------------
template <bool RELU>
__global__ __launch_bounds__(256) void k_agg64(const __half* __restrict__ Hh,
                                               const int* __restrict__ offs,
                                               const int* __restrict__ csr,
                                               const float* __restrict__ dinv,
                                               const float* __restrict__ bias,
                                               float* __restrict__ Y, int N) {
    int node = blockIdx.x * 4 + (threadIdx.x >> 6);
    int lane = threadIdx.x & 63;
    if (node >= N) return;
    float acc = 0.f;
    int o0 = offs[node], o1 = offs[node + 1];
    int e = o0;
    for (; e + 4 <= o1; e += 4) {
        int s0 = csr[e], s1 = csr[e + 1], s2 = csr[e + 2], s3 = csr[e + 3];
        float v0 = __half2float(Hh[(size_t)s0 * 64 + lane]);
        float v1 = __half2float(Hh[(size_t)s1 * 64 + lane]);
        float v2 = __half2float(Hh[(size_t)s2 * 64 + lane]);
        float v3 = __half2float(Hh[(size_t)s3 * 64 + lane]);
        acc += (v0 + v1) + (v2 + v3);
    }
    for (; e < o1; ++e)
        acc += __half2float(Hh[(size_t)csr[e] * 64 + lane]);
    float fs = __half2float(Hh[(size_t)node * 64 + lane]);
    float di = dinv[node];
    float v = di * (acc + fs) + bias[lane];
    if (RELU) v = v > 0.f ? v : 0.2f * v;
    Y[(size_t)node * 64 + lane] = v;
}

extern "C" void kernel_launch(void* const* d_in, const int* in_sizes, int n_in,
                              void* d_out, int out_size, void* d_ws, size_t ws_size,
                              hipStream_t stream) {
    const float* x  = (const float*)d_in[0];
    const int*   ei = (const int*)d_in[1];
    const float* W1 = (const float*)d_in[2];
    const float* b1 = (const float*)d_in[3];
    const float* W2 = (const float*)d_in[4];
    const float* b2 = (const float*)d_in[5];
    const float* W3 = (const float*)d_in[6];
    const float* b3 = (const float*)d_in[7];

    const int N = in_sizes[0] / 512;
    const int E = in_sizes[1] / 2;
    const int nb = (N + 255) / 256;

    char* w = (char*)d_ws;
    auto take = [&](size_t bytes) -> char* {
        char* p = w;
        w += alignup(bytes, 256);
        return p;
    };
    int*    flag  = (int*)take(256);
    int*    deg   = (int*)take((size_t)N * 4);
    int*    cnt   = (int*)take((size_t)N * 4);
    int*    offs  = (int*)take((size_t)(N + 1) * 4);
    int*    bsums = (int*)take((size_t)nb * 4);
    int*    boffs = (int*)take((size_t)nb * 4);
    int*    csr   = (int*)take((size_t)E * 4);
    float*  dinv  = (float*)take((size_t)N * 4);
    __half* bufA  = (__half*)take((size_t)N * 128 * 2);   // H' fp16
    float*  bufB  = (float*)take((size_t)N * 128 * 4);    // agg out f32
    u16*    w1h   = (u16*)take((size_t)512 * 128 * 2);
    u16*    w1l   = (u16*)take((size_t)512 * 128 * 2);
    u16*    w2h   = (u16*)take((size_t)128 * 64 * 2);
    u16*    w2l   = (u16*)take((size_t)128 * 64 * 2);
    u16*    w3h   = (u16*)take((size_t)64 * 64 * 2);
    u16*    w3l   = (u16*)take((size_t)64 * 64 * 2);

    const int TB = 256;
    // preprocessing
    k_detect<<<1, 64, 0, stream>>>(ei, flag);
    k_zero2<<<(N + TB - 1) / TB, TB, 0, stream>>>(deg, cnt, N);
    k_deg<<<(E + TB - 1) / TB, TB, 0, stream>>>(ei, E, flag, deg);
    k_dinv<<<(N + TB - 1) / TB, TB, 0, stream>>>(deg, dinv, N);
    k_scan1<<<nb, 256, 0, stream>>>(deg, offs, bsums, N);
    k_scan2<<<1, 256, 0, stream>>>(bsums, boffs, nb);
    k_scan3<<<(N + TB - 1) / TB, TB, 0, stream>>>(offs, boffs, N, E);
    k_fill<<<(E + TB - 1) / TB, TB, 0, stream>>>(ei, E, flag, offs, cnt, csr);
    // W splits
    k_splitW<512, 128><<<(512 * 128 / 8 + 255) / 256, 256, 0, stream>>>(W1, w1h, w1l);
    k_splitW<128, 64><<<(128 * 64 / 8 + 255) / 256, 256, 0, stream>>>(W2, w2h, w2l);
    k_splitW<64, 64><<<(64 * 64 / 8 + 255) / 256, 256, 0, stream>>>(W3, w3h, w3l);

    const int gemm_grid = (N + 127) / 128;
    const int agg_grid = (N + 3) / 4;
    // layer 1
    k_gemm_mfma<512, 128><<<gemm_grid, 256, 0, stream>>>(x, w1h, w1l, dinv, bufA, N);
    k_agg128<true><<<agg_grid, 256, 0, stream>>>(bufA, offs, csr, dinv, b1, bufB, N);
    // layer 2
    k_gemm_mfma<128, 64><<<gemm_grid, 256, 0, stream>>>(bufB, w2h, w2l, dinv, bufA, N);
    k_agg64<true><<<agg_grid, 256, 0, stream>>>(bufA, offs, csr, dinv, b2, bufB, N);
    // layer 3 (no relu), write straight to output
    k_gemm_mfma<64, 64><<<gemm_grid, 256, 0, stream>>>(bufB, w3h, w3l, dinv, bufA, N);
    k_agg64<false><<<agg_grid, 256, 0, stream>>>(bufA, offs, csr, dinv, b3,
                                                 (float*)d_out, N);
}

// Round 5
// 266.485 us; speedup vs baseline: 2.0332x; 1.0436x over previous
//
#include <hip/hip_runtime.h>
#include <hip/hip_fp16.h>

// ---------------------------------------------------------------------------
// GCN 3-layer forward on MI355X.
// detect edge layout -> deg -> dinv -> scan -> CSR fill -> W-split x3
//   -> [MFMA GEMM (bf16x3 split of f32) + dinv-scaled fp16 epilogue -> AGG] x3
// GEMM: no LDS/barriers; B pre-split bf16 hi/lo fragment-ordered (L2-resident),
//       A f32 global split in-register. 64-row blocks (grid ~782) for >=3
//       waves/SIMD occupancy. Epilogue writes H' = dinv[row]*h, fp16.
// AGG:  per-dst gather of fp16 H' rows; F=128 wave/node, F=64 half-wave/node.
//       y = dinv_d*(sum H'[s] + H'[d]) + b  (dinv folded at both ends).
// ---------------------------------------------------------------------------

typedef __attribute__((ext_vector_type(8))) short bf16x8;
typedef __attribute__((ext_vector_type(4))) float f32x4;
typedef unsigned short u16;
typedef unsigned int u32;

static inline size_t alignup(size_t v, size_t a) { return (v + a - 1) & ~(a - 1); }

// pack top-16 bits of two f32 bit patterns into one u32 (lo half from b0)
__device__ __forceinline__ u32 pack_hi16(u32 b0, u32 b1) {
    return __builtin_amdgcn_perm(b1, b0, 0x07060302u);
}

// --- edge dtype detect: if input is int64, every odd 32-bit word is 0 -------
__global__ void k_detect(const int* __restrict__ ei, int* __restrict__ flag) {
    int v = ei[2 * threadIdx.x + 1];
    unsigned long long b = __ballot(v != 0);
    if (threadIdx.x == 0) *flag = (b == 0ull) ? 1 : 0;   // 1 => int64 layout
}

__global__ void k_zero2(int* __restrict__ a, int* __restrict__ b, int n) {
    int i = blockIdx.x * blockDim.x + threadIdx.x;
    if (i < n) { a[i] = 0; b[i] = 0; }
}

__global__ void k_deg(const int* __restrict__ ei, int E,
                      const int* __restrict__ flag, int* __restrict__ deg) {
    int i = blockIdx.x * blockDim.x + threadIdx.x;
    if (i >= E) return;
    int is64 = *flag;
    int d = is64 ? ei[2 * (E + i)] : ei[E + i];
    atomicAdd(&deg[d], 1);
}

__global__ void k_dinv(const int* __restrict__ deg, float* __restrict__ dinv, int N) {
    int i = blockIdx.x * blockDim.x + threadIdx.x;
    if (i < N) dinv[i] = rsqrtf((float)deg[i] + 1.0f);
}

// --- 3-kernel exclusive scan over deg (256 elems/block) ---------------------
__global__ void k_scan1(const int* __restrict__ deg, int* __restrict__ offs,
                        int* __restrict__ bsums, int N) {
    __shared__ int s[256];
    int i = blockIdx.x * 256 + threadIdx.x;
    int v = (i < N) ? deg[i] : 0;
    s[threadIdx.x] = v;
    __syncthreads();
    for (int off = 1; off < 256; off <<= 1) {
        int t = (threadIdx.x >= off) ? s[threadIdx.x - off] : 0;
        __syncthreads();
        s[threadIdx.x] += t;
        __syncthreads();
    }
    if (i < N) offs[i] = s[threadIdx.x] - v;   // exclusive
    if (threadIdx.x == 255) bsums[blockIdx.x] = s[255];
}

__global__ void k_scan2(const int* __restrict__ bsums, int* __restrict__ boffs, int nb) {
    __shared__ int s[256];
    int i = threadIdx.x;
    int v = (i < nb) ? bsums[i] : 0;
    s[i] = v;
    __syncthreads();
    for (int off = 1; off < 256; off <<= 1) {
        int t = (i >= off) ? s[i - off] : 0;
        __syncthreads();
        s[i] += t;
        __syncthreads();
    }
    if (i < nb) boffs[i] = s[i] - v;
}

__global__ void k_scan3(int* __restrict__ offs, const int* __restrict__ boffs,
                        int N, int E) {
    int i = blockIdx.x * blockDim.x + threadIdx.x;
    if (i < N) offs[i] += boffs[i >> 8];
    if (i == 0) offs[N] = E;
}

__global__ void k_fill(const int* __restrict__ ei, int E,
                       const int* __restrict__ flag,
                       const int* __restrict__ offs, int* __restrict__ cnt,
                       int* __restrict__ csr) {
    int i = blockIdx.x * blockDim.x + threadIdx.x;
    if (i >= E) return;
    int is64 = *flag;
    int s = is64 ? ei[2 * i] : ei[i];
    int d = is64 ? ei[2 * (E + i)] : ei[E + i];
    int slot = offs[d] + atomicAdd(&cnt[d], 1);
    csr[slot] = s;
}

// --- W pre-split into fragment-ordered bf16 hi/lo ----------------------------
// slot s = ((t*4+g)*F + c) holds W[t*32+g*8+j][c], j=0..7, as 8 bf16 (16 B).
template <int K, int F>
__global__ void k_splitW(const float* __restrict__ W, u16* __restrict__ Wh,
                         u16* __restrict__ Wl) {
    int s = blockIdx.x * 256 + threadIdx.x;
    if (s >= K * F / 8) return;
    int c = s % F;
    int kb = (s / F) * 8;
    union { u32 u[4]; bf16x8 v; } hi, lo;
#pragma unroll
    for (int p = 0; p < 4; p++) {
        float x0 = W[(size_t)(kb + 2 * p) * F + c];
        float x1 = W[(size_t)(kb + 2 * p + 1) * F + c];
        u32 b0 = __float_as_uint(x0), b1 = __float_as_uint(x1);
        float l0 = x0 - __uint_as_float(b0 & 0xFFFF0000u);
        float l1 = x1 - __uint_as_float(b1 & 0xFFFF0000u);
        hi.u[p] = pack_hi16(b0, b1);
        lo.u[p] = pack_hi16(__float_as_uint(l0), __float_as_uint(l1));
    }
    *(bf16x8*)(Wh + (size_t)s * 8) = hi.v;
    *(bf16x8*)(Wl + (size_t)s * 8) = lo.v;
}

// --- MFMA GEMM: H'[N,F] = dinv_row * (X[N,K] @ W[K,F]), fp16 out -------------
// 256 thr = 4 waves; block = 64 rows x F cols; grid = (N+63)/64.
// F=128: wave tile 32x64 (MF=2, 2 col-halves); F=64: wave tile 16x64 (MF=1).
template <int K, int F>
__global__ __launch_bounds__(256) void k_gemm_mfma(const float* __restrict__ X,
        const u16* __restrict__ Wh, const u16* __restrict__ Wl,
        const float* __restrict__ dinv, __half* __restrict__ Hh, int N) {
    constexpr int WNW = F / 64;
    constexpr int MF = WNW;            // 2 for F=128, 1 for F=64
    constexpr int NF = 4;
    const int tid = threadIdx.x;
    const int w = tid >> 6, lane = tid & 63;
    const int wm = w / WNW, wn = w % WNW;
    const int lg = lane >> 4, li = lane & 15;
    const int row0 = blockIdx.x * 64 + wm * (MF * 16);
    const int colbase = wn * 64;

    const float* xrow[MF];
#pragma unroll
    for (int m = 0; m < MF; m++) {
        int r = row0 + m * 16 + li;
        xrow[m] = X + (size_t)(r < N ? r : N - 1) * K;
    }

    f32x4 acc[MF][NF];
#pragma unroll
    for (int m = 0; m < MF; m++)
#pragma unroll
        for (int n = 0; n < NF; n++) acc[m][n] = (f32x4){0.f, 0.f, 0.f, 0.f};

#pragma unroll 2
    for (int t = 0; t < K / 32; t++) {
        // B fragments: direct coalesced 16B loads (L1/L2-resident)
        bf16x8 bh[NF], bl[NF];
        size_t slot0 = (size_t)(t * 4 + lg) * F + colbase + li;
#pragma unroll
        for (int n = 0; n < NF; n++) {
            bh[n] = *(const bf16x8*)(Wh + (slot0 + n * 16) * 8);
            bl[n] = *(const bf16x8*)(Wl + (slot0 + n * 16) * 8);
        }
        // A fragments: 8 consecutive f32 -> hi/lo bf16x8 (in-register split)
        bf16x8 ah[MF], al[MF];
#pragma unroll
        for (int m = 0; m < MF; m++) {
            const float* p = xrow[m] + t * 32 + lg * 8;
            float4 a0 = *(const float4*)p;
            float4 a1 = *(const float4*)(p + 4);
            float x[8] = {a0.x, a0.y, a0.z, a0.w, a1.x, a1.y, a1.z, a1.w};
            union { u32 u[4]; bf16x8 v; } hi, lo;
#pragma unroll
            for (int q = 0; q < 4; q++) {
                u32 b0 = __float_as_uint(x[2 * q]);
                u32 b1 = __float_as_uint(x[2 * q + 1]);
                float l0 = x[2 * q]     - __uint_as_float(b0 & 0xFFFF0000u);
                float l1 = x[2 * q + 1] - __uint_as_float(b1 & 0xFFFF0000u);
                hi.u[q] = pack_hi16(b0, b1);
                lo.u[q] = pack_hi16(__float_as_uint(l0), __float_as_uint(l1));
            }
            ah[m] = hi.v;
            al[m] = lo.v;
        }
        // 3-product accumulation: xh*wh + xh*wl + xl*wh
#pragma unroll
        for (int m = 0; m < MF; m++)
#pragma unroll
            for (int n = 0; n < NF; n++) {
                acc[m][n] = __builtin_amdgcn_mfma_f32_16x16x32_bf16(ah[m], bh[n], acc[m][n], 0, 0, 0);
                acc[m][n] = __builtin_amdgcn_mfma_f32_16x16x32_bf16(ah[m], bl[n], acc[m][n], 0, 0, 0);
                acc[m][n] = __builtin_amdgcn_mfma_f32_16x16x32_bf16(al[m], bh[n], acc[m][n], 0, 0, 0);
            }
    }

    // C/D layout: col = lane&15, row = (lane>>4)*4 + reg (m89-verified)
    // Epilogue folds dinv[row] and converts to fp16.
#pragma unroll
    for (int m = 0; m < MF; m++) {
        int rb = row0 + m * 16 + lg * 4;
#pragma unroll
        for (int r = 0; r < 4; r++) {
            int gr = rb + r;
            if (gr >= N) continue;
            float di = dinv[gr];
#pragma unroll
            for (int n = 0; n < NF; n++) {
                int col = colbase + n * 16 + li;
                Hh[(size_t)gr * F + col] = __float2half(acc[m][n][r] * di);
            }
        }
    }
}

// --- aggregation, F=128, fp16 H' in, f32 out ---------------------------------
// y = act(dinv_d * (sum_s H'[s] + H'[d]) + b); one wave per node; 4-edge unroll.
template <bool RELU>
__global__ __launch_bounds__(256) void k_agg128(const __half* __restrict__ Hh,
                                                const int* __restrict__ offs,
                                                const int* __restrict__ csr,
                                                const float* __restrict__ dinv,
                                                const float* __restrict__ bias,
                                                float* __restrict__ Y, int N) {
    int node = blockIdx.x * 4 + (threadIdx.x >> 6);
    int lane = threadIdx.x & 63;
    if (node >= N) return;
    const __half2* H2 = (const __half2*)Hh;   // row = 64 half2
    float ax = 0.f, ay = 0.f;
    int o0 = offs[node], o1 = offs[node + 1];
    int e = o0;
    for (; e + 4 <= o1; e += 4) {
        int s0 = csr[e], s1 = csr[e + 1], s2 = csr[e + 2], s3 = csr[e + 3];
        __half2 v0 = H2[(size_t)s0 * 64 + lane];
        __half2 v1 = H2[(size_t)s1 * 64 + lane];
        __half2 v2 = H2[(size_t)s2 * 64 + lane];
        __half2 v3 = H2[(size_t)s3 * 64 + lane];
        float2 f0 = __half22float2(v0), f1 = __half22float2(v1);
        float2 f2 = __half22float2(v2), f3 = __half22float2(v3);
        ax += (f0.x + f1.x) + (f2.x + f3.x);
        ay += (f0.y + f1.y) + (f2.y + f3.y);
    }
    for (; e < o1; ++e) {
        float2 f0 = __half22float2(H2[(size_t)csr[e] * 64 + lane]);
        ax += f0.x; ay += f0.y;
    }
    float2 fs = __half22float2(H2[(size_t)node * 64 + lane]);
    float di = dinv[node];
    float2 bv = ((const float2*)bias)[lane];
    float vx = di * (ax + fs.x) + bv.x;
    float vy = di * (ay + fs.y) + bv.y;
    if (RELU) { vx = vx > 0.f ? vx : 0.2f * vx; vy = vy > 0.f ? vy : 0.2f * vy; }
    ((float2*)Y)[(size_t)node * 64 + lane] = make_float2(vx, vy);
}

// --- aggregation, F=64, fp16 H' in, f32 out ----------------------------------
// Half-wave (32 lanes) per node: fp16 row = 128 B = 32 x half2. 8 nodes/block.
template <bool RELU>
__global__ __launch_bounds__(256) void k_agg64(const __half* __restrict__ Hh,
                                               const int* __restrict__ offs,
                                               const int* __restrict__ csr,
                                               const float* __restrict__ dinv,
                                               const float* __restrict__ bias,
                                               float* __restrict__ Y, int N) {
    int node = blockIdx.x * 8 + (threadIdx.x >> 5);
    int lane = threadIdx.x & 31;
    if (node >= N) return;
    const __half2* H2 = (const __half2*)Hh;   // row = 32 half2
    float ax = 0.f, ay = 0.f;
    int o0 = offs[node], o1 = offs[node + 1];
    int e = o0;
    for (; e + 4 <= o1; e += 4) {
        int s0 = csr[e], s1 = csr[e + 1], s2 = csr[e + 2], s3 = csr[e + 3];
        float2 f0 = __half22float2(H2[(size_t)s0 * 32 + lane]);
        float2 f1 = __half22float2(H2[(size_t)s1 * 32 + lane]);
        float2 f2 = __half22float2(H2[(size_t)s2 * 32 + lane]);
        float2 f3 = __half22float2(H2[(size_t)s3 * 32 + lane]);
        ax += (f0.x + f1.x) + (f2.x + f3.x);
        ay += (f0.y + f1.y) + (f2.y + f3.y);
    }
    for (; e < o1; ++e) {
        float2 f0 = __half22float2(H2[(size_t)csr[e] * 32 + lane]);
        ax += f0.x; ay += f0.y;
    }
    float2 fs = __half22float2(H2[(size_t)node * 32 + lane]);
    float di = dinv[node];
    float2 bv = ((const float2*)bias)[lane];
    float vx = di * (ax + fs.x) + bv.x;
    float vy = di * (ay + fs.y) + bv.y;
    if (RELU) { vx = vx > 0.f ? vx : 0.2f * vx; vy = vy > 0.f ? vy : 0.2f * vy; }
    ((float2*)Y)[(size_t)node * 32 + lane] = make_float2(vx, vy);
}

extern "C" void kernel_launch(void* const* d_in, const int* in_sizes, int n_in,
                              void* d_out, int out_size, void* d_ws, size_t ws_size,
                              hipStream_t stream) {
    const float* x  = (const float*)d_in[0];
    const int*   ei = (const int*)d_in[1];
    const float* W1 = (const float*)d_in[2];
    const float* b1 = (const float*)d_in[3];
    const float* W2 = (const float*)d_in[4];
    const float* b2 = (const float*)d_in[5];
    const float* W3 = (const float*)d_in[6];
    const float* b3 = (const float*)d_in[7];

    const int N = in_sizes[0] / 512;
    const int E = in_sizes[1] / 2;
    const int nb = (N + 255) / 256;

    char* w = (char*)d_ws;
    auto take = [&](size_t bytes) -> char* {
        char* p = w;
        w += alignup(bytes, 256);
        return p;
    };
    int*    flag  = (int*)take(256);
    int*    deg   = (int*)take((size_t)N * 4);
    int*    cnt   = (int*)take((size_t)N * 4);
    int*    offs  = (int*)take((size_t)(N + 1) * 4);
    int*    bsums = (int*)take((size_t)nb * 4);
    int*    boffs = (int*)take((size_t)nb * 4);
    int*    csr   = (int*)take((size_t)E * 4);
    float*  dinv  = (float*)take((size_t)N * 4);
    __half* bufA  = (__half*)take((size_t)N * 128 * 2);   // H' fp16
    float*  bufB  = (float*)take((size_t)N * 128 * 4);    // agg out f32
    u16*    w1h   = (u16*)take((size_t)512 * 128 * 2);
    u16*    w1l   = (u16*)take((size_t)512 * 128 * 2);
    u16*    w2h   = (u16*)take((size_t)128 * 64 * 2);
    u16*    w2l   = (u16*)take((size_t)128 * 64 * 2);
    u16*    w3h   = (u16*)take((size_t)64 * 64 * 2);
    u16*    w3l   = (u16*)take((size_t)64 * 64 * 2);

    const int TB = 256;
    // preprocessing
    k_detect<<<1, 64, 0, stream>>>(ei, flag);
    k_zero2<<<(N + TB - 1) / TB, TB, 0, stream>>>(deg, cnt, N);
    k_deg<<<(E + TB - 1) / TB, TB, 0, stream>>>(ei, E, flag, deg);
    k_dinv<<<(N + TB - 1) / TB, TB, 0, stream>>>(deg, dinv, N);
    k_scan1<<<nb, 256, 0, stream>>>(deg, offs, bsums, N);
    k_scan2<<<1, 256, 0, stream>>>(bsums, boffs, nb);
    k_scan3<<<(N + TB - 1) / TB, TB, 0, stream>>>(offs, boffs, N, E);
    k_fill<<<(E + TB - 1) / TB, TB, 0, stream>>>(ei, E, flag, offs, cnt, csr);
    // W splits
    k_splitW<512, 128><<<(512 * 128 / 8 + 255) / 256, 256, 0, stream>>>(W1, w1h, w1l);
    k_splitW<128, 64><<<(128 * 64 / 8 + 255) / 256, 256, 0, stream>>>(W2, w2h, w2l);
    k_splitW<64, 64><<<(64 * 64 / 8 + 255) / 256, 256, 0, stream>>>(W3, w3h, w3l);

    const int gemm_grid = (N + 63) / 64;
    // layer 1
    k_gemm_mfma<512, 128><<<gemm_grid, 256, 0, stream>>>(x, w1h, w1l, dinv, bufA, N);
    k_agg128<true><<<(N + 3) / 4, 256, 0, stream>>>(bufA, offs, csr, dinv, b1, bufB, N);
    // layer 2
    k_gemm_mfma<128, 64><<<gemm_grid, 256, 0, stream>>>(bufB, w2h, w2l, dinv, bufA, N);
    k_agg64<true><<<(N + 7) / 8, 256, 0, stream>>>(bufA, offs, csr, dinv, b2, bufB, N);
    // layer 3 (no relu), write straight to output
    k_gemm_mfma<64, 64><<<gemm_grid, 256, 0, stream>>>(bufB, w3h, w3l, dinv, bufA, N);
    k_agg64<false><<<(N + 7) / 8, 256, 0, stream>>>(bufA, offs, csr, dinv, b3,
                                                    (float*)d_out, N);
}

// Round 6
// 257.107 us; speedup vs baseline: 2.1074x; 1.0365x over previous
//
#include <hip/hip_runtime.h>
#include <hip/hip_fp16.h>

// ---------------------------------------------------------------------------
// GCN 3-layer forward on MI355X.
// detect edge layout -> deg -> dinv -> scan -> CSR fill -> W-split x3
//   -> [MFMA GEMM (bf16x3 split of f32) + dinv-scaled fp16 epilogue -> AGG] x3
// GEMM: no LDS/barriers. Wave tile 64x64 (MF=4,NF=4) for max per-wave ILP;
//       64-row blocks (grid 782, ~3 blocks/CU, balanced); register
//       double-buffer of raw A float4s (prefetch t+1 during MFMA of t).
//       B pre-split bf16 hi/lo fragment-ordered, L1/L2-resident.
// AGG:  per-dst gather of fp16 H' rows; F=128 wave/node, F=64 half-wave/node.
//       y = dinv_d*(sum H'[s] + H'[d]) + b  (dinv folded at both ends).
// ---------------------------------------------------------------------------

typedef __attribute__((ext_vector_type(8))) short bf16x8;
typedef __attribute__((ext_vector_type(4))) float f32x4;
typedef unsigned short u16;
typedef unsigned int u32;

static inline size_t alignup(size_t v, size_t a) { return (v + a - 1) & ~(a - 1); }

// pack top-16 bits of two f32 bit patterns into one u32 (lo half from b0)
__device__ __forceinline__ u32 pack_hi16(u32 b0, u32 b1) {
    return __builtin_amdgcn_perm(b1, b0, 0x07060302u);
}

// --- edge dtype detect: if input is int64, every odd 32-bit word is 0 -------
__global__ void k_detect(const int* __restrict__ ei, int* __restrict__ flag) {
    int v = ei[2 * threadIdx.x + 1];
    unsigned long long b = __ballot(v != 0);
    if (threadIdx.x == 0) *flag = (b == 0ull) ? 1 : 0;   // 1 => int64 layout
}

__global__ void k_zero2(int* __restrict__ a, int* __restrict__ b, int n) {
    int i = blockIdx.x * blockDim.x + threadIdx.x;
    if (i < n) { a[i] = 0; b[i] = 0; }
}

__global__ void k_deg(const int* __restrict__ ei, int E,
                      const int* __restrict__ flag, int* __restrict__ deg) {
    int i = blockIdx.x * blockDim.x + threadIdx.x;
    if (i >= E) return;
    int is64 = *flag;
    int d = is64 ? ei[2 * (E + i)] : ei[E + i];
    atomicAdd(&deg[d], 1);
}

__global__ void k_dinv(const int* __restrict__ deg, float* __restrict__ dinv, int N) {
    int i = blockIdx.x * blockDim.x + threadIdx.x;
    if (i < N) dinv[i] = rsqrtf((float)deg[i] + 1.0f);
}

// --- 3-kernel exclusive scan over deg (256 elems/block) ---------------------
__global__ void k_scan1(const int* __restrict__ deg, int* __restrict__ offs,
                        int* __restrict__ bsums, int N) {
    __shared__ int s[256];
    int i = blockIdx.x * 256 + threadIdx.x;
    int v = (i < N) ? deg[i] : 0;
    s[threadIdx.x] = v;
    __syncthreads();
    for (int off = 1; off < 256; off <<= 1) {
        int t = (threadIdx.x >= off) ? s[threadIdx.x - off] : 0;
        __syncthreads();
        s[threadIdx.x] += t;
        __syncthreads();
    }
    if (i < N) offs[i] = s[threadIdx.x] - v;   // exclusive
    if (threadIdx.x == 255) bsums[blockIdx.x] = s[255];
}

__global__ void k_scan2(const int* __restrict__ bsums, int* __restrict__ boffs, int nb) {
    __shared__ int s[256];
    int i = threadIdx.x;
    int v = (i < nb) ? bsums[i] : 0;
    s[i] = v;
    __syncthreads();
    for (int off = 1; off < 256; off <<= 1) {
        int t = (i >= off) ? s[i - off] : 0;
        __syncthreads();
        s[i] += t;
        __syncthreads();
    }
    if (i < nb) boffs[i] = s[i] - v;
}

__global__ void k_scan3(int* __restrict__ offs, const int* __restrict__ boffs,
                        int N, int E) {
    int i = blockIdx.x * blockDim.x + threadIdx.x;
    if (i < N) offs[i] += boffs[i >> 8];
    if (i == 0) offs[N] = E;
}

__global__ void k_fill(const int* __restrict__ ei, int E,
                       const int* __restrict__ flag,
                       const int* __restrict__ offs, int* __restrict__ cnt,
                       int* __restrict__ csr) {
    int i = blockIdx.x * blockDim.x + threadIdx.x;
    if (i >= E) return;
    int is64 = *flag;
    int s = is64 ? ei[2 * i] : ei[i];
    int d = is64 ? ei[2 * (E + i)] : ei[E + i];
    int slot = offs[d] + atomicAdd(&cnt[d], 1);
    csr[slot] = s;
}

// --- W pre-split into fragment-ordered bf16 hi/lo ----------------------------
// slot s = ((t*4+g)*F + c) holds W[t*32+g*8+j][c], j=0..7, as 8 bf16 (16 B).
template <int K, int F>
__global__ void k_splitW(const float* __restrict__ W, u16* __restrict__ Wh,
                         u16* __restrict__ Wl) {
    int s = blockIdx.x * 256 + threadIdx.x;
    if (s >= K * F / 8) return;
    int c = s % F;
    int kb = (s / F) * 8;
    union { u32 u[4]; bf16x8 v; } hi, lo;
#pragma unroll
    for (int p = 0; p < 4; p++) {
        float x0 = W[(size_t)(kb + 2 * p) * F + c];
        float x1 = W[(size_t)(kb + 2 * p + 1) * F + c];
        u32 b0 = __float_as_uint(x0), b1 = __float_as_uint(x1);
        float l0 = x0 - __uint_as_float(b0 & 0xFFFF0000u);
        float l1 = x1 - __uint_as_float(b1 & 0xFFFF0000u);
        hi.u[p] = pack_hi16(b0, b1);
        lo.u[p] = pack_hi16(__float_as_uint(l0), __float_as_uint(l1));
    }
    *(bf16x8*)(Wh + (size_t)s * 8) = hi.v;
    *(bf16x8*)(Wl + (size_t)s * 8) = lo.v;
}

// --- MFMA GEMM: H'[N,F] = dinv_row * (X[N,K] @ W[K,F]), fp16 out -------------
// One wave per 64-row x 64-col tile (MF=4, NF=4). Block = WNW waves covering
// F columns; grid = (N+63)/64. Raw-A register double buffer across K-steps.
template <int K, int F>
__global__ __launch_bounds__(F == 128 ? 128 : 64) void k_gemm_mfma(
        const float* __restrict__ X,
        const u16* __restrict__ Wh, const u16* __restrict__ Wl,
        const float* __restrict__ dinv, __half* __restrict__ Hh, int N) {
    constexpr int WNW = F / 64;        // waves per block (column slices)
    constexpr int MF = 4;
    constexpr int NF = 4;
    constexpr int NT = K / 32;         // K-steps
    const int tid = threadIdx.x;
    const int lane = tid & 63;
    const int wn = tid >> 6;           // 0..WNW-1
    const int lg = lane >> 4, li = lane & 15;
    const int row0 = blockIdx.x * 64;
    const int colbase = wn * 64;

    const float* xrow[MF];
#pragma unroll
    for (int m = 0; m < MF; m++) {
        int r = row0 + m * 16 + li;
        xrow[m] = X + (size_t)(r < N ? r : N - 1) * K;
    }

    f32x4 acc[MF][NF];
#pragma unroll
    for (int m = 0; m < MF; m++)
#pragma unroll
        for (int n = 0; n < NF; n++) acc[m][n] = (f32x4){0.f, 0.f, 0.f, 0.f};

    // prologue: raw A for t=0
    float4 acur[MF][2];
#pragma unroll
    for (int m = 0; m < MF; m++) {
        const float* p = xrow[m] + lg * 8;
        acur[m][0] = *(const float4*)p;
        acur[m][1] = *(const float4*)(p + 4);
    }

#pragma unroll 2
    for (int t = 0; t < NT; t++) {
        // B(t) fragments: direct coalesced 16B loads (L1/L2-resident)
        bf16x8 bh[NF], bl[NF];
        size_t slot0 = (size_t)(t * 4 + lg) * F + colbase + li;
#pragma unroll
        for (int n = 0; n < NF; n++) {
            bh[n] = *(const bf16x8*)(Wh + (slot0 + n * 16) * 8);
            bl[n] = *(const bf16x8*)(Wl + (slot0 + n * 16) * 8);
        }
        // A(t+1) prefetch: issue before compute so MFMA phase hides latency
        float4 anxt[MF][2];
        if (t + 1 < NT) {
#pragma unroll
            for (int m = 0; m < MF; m++) {
                const float* p = xrow[m] + (t + 1) * 32 + lg * 8;
                anxt[m][0] = *(const float4*)p;
                anxt[m][1] = *(const float4*)(p + 4);
            }
        }
        // split acur -> hi/lo bf16x8 (independent VALU; hides B latency)
        bf16x8 ah[MF], al[MF];
#pragma unroll
        for (int m = 0; m < MF; m++) {
            float xv[8] = {acur[m][0].x, acur[m][0].y, acur[m][0].z, acur[m][0].w,
                           acur[m][1].x, acur[m][1].y, acur[m][1].z, acur[m][1].w};
            union { u32 u[4]; bf16x8 v; } hi, lo;
#pragma unroll
            for (int q = 0; q < 4; q++) {
                u32 b0 = __float_as_uint(xv[2 * q]);
                u32 b1 = __float_as_uint(xv[2 * q + 1]);
                float l0 = xv[2 * q]     - __uint_as_float(b0 & 0xFFFF0000u);
                float l1 = xv[2 * q + 1] - __uint_as_float(b1 & 0xFFFF0000u);
                hi.u[q] = pack_hi16(b0, b1);
                lo.u[q] = pack_hi16(__float_as_uint(l0), __float_as_uint(l1));
            }
            ah[m] = hi.v;
            al[m] = lo.v;
        }
        // 3-product accumulation: xh*wh + xh*wl + xl*wh
#pragma unroll
        for (int m = 0; m < MF; m++)
#pragma unroll
            for (int n = 0; n < NF; n++) {
                acc[m][n] = __builtin_amdgcn_mfma_f32_16x16x32_bf16(ah[m], bh[n], acc[m][n], 0, 0, 0);
                acc[m][n] = __builtin_amdgcn_mfma_f32_16x16x32_bf16(ah[m], bl[n], acc[m][n], 0, 0, 0);
                acc[m][n] = __builtin_amdgcn_mfma_f32_16x16x32_bf16(al[m], bh[n], acc[m][n], 0, 0, 0);
            }
        // rotate A buffers
#pragma unroll
        for (int m = 0; m < MF; m++) {
            acur[m][0] = anxt[m][0];
            acur[m][1] = anxt[m][1];
        }
    }

    // C/D layout: col = lane&15, row = (lane>>4)*4 + reg (m89-verified)
    // Epilogue folds dinv[row] and converts to fp16.
#pragma unroll
    for (int m = 0; m < MF; m++) {
        int rb = row0 + m * 16 + lg * 4;
#pragma unroll
        for (int r = 0; r < 4; r++) {
            int gr = rb + r;
            if (gr >= N) continue;
            float di = dinv[gr];
#pragma unroll
            for (int n = 0; n < NF; n++) {
                int col = colbase + n * 16 + li;
                Hh[(size_t)gr * F + col] = __float2half(acc[m][n][r] * di);
            }
        }
    }
}

// --- aggregation, F=128, fp16 H' in, f32 out ---------------------------------
// y = act(dinv_d * (sum_s H'[s] + H'[d]) + b); one wave per node; 4-edge unroll.
template <bool RELU>
__global__ __launch_bounds__(256) void k_agg128(const __half* __restrict__ Hh,
                                                const int* __restrict__ offs,
                                                const int* __restrict__ csr,
                                                const float* __restrict__ dinv,
                                                const float* __restrict__ bias,
                                                float* __restrict__ Y, int N) {
    int node = blockIdx.x * 4 + (threadIdx.x >> 6);
    int lane = threadIdx.x & 63;
    if (node >= N) return;
    const __half2* H2 = (const __half2*)Hh;   // row = 64 half2
    float ax = 0.f, ay = 0.f;
    int o0 = offs[node], o1 = offs[node + 1];
    int e = o0;
    for (; e + 4 <= o1; e += 4) {
        int s0 = csr[e], s1 = csr[e + 1], s2 = csr[e + 2], s3 = csr[e + 3];
        __half2 v0 = H2[(size_t)s0 * 64 + lane];
        __half2 v1 = H2[(size_t)s1 * 64 + lane];
        __half2 v2 = H2[(size_t)s2 * 64 + lane];
        __half2 v3 = H2[(size_t)s3 * 64 + lane];
        float2 f0 = __half22float2(v0), f1 = __half22float2(v1);
        float2 f2 = __half22float2(v2), f3 = __half22float2(v3);
        ax += (f0.x + f1.x) + (f2.x + f3.x);
        ay += (f0.y + f1.y) + (f2.y + f3.y);
    }
    for (; e < o1; ++e) {
        float2 f0 = __half22float2(H2[(size_t)csr[e] * 64 + lane]);
        ax += f0.x; ay += f0.y;
    }
    float2 fs = __half22float2(H2[(size_t)node * 64 + lane]);
    float di = dinv[node];
    float2 bv = ((const float2*)bias)[lane];
    float vx = di * (ax + fs.x) + bv.x;
    float vy = di * (ay + fs.y) + bv.y;
    if (RELU) { vx = vx > 0.f ? vx : 0.2f * vx; vy = vy > 0.f ? vy : 0.2f * vy; }
    ((float2*)Y)[(size_t)node * 64 + lane] = make_float2(vx, vy);
}

// --- aggregation, F=64, fp16 H' in, f32 out ----------------------------------
// Half-wave (32 lanes) per node: fp16 row = 128 B = 32 x half2. 8 nodes/block.
template <bool RELU>
__global__ __launch_bounds__(256) void k_agg64(const __half* __restrict__ Hh,
                                               const int* __restrict__ offs,
                                               const int* __restrict__ csr,
                                               const float* __restrict__ dinv,
                                               const float* __restrict__ bias,
                                               float* __restrict__ Y, int N) {
    int node = blockIdx.x * 8 + (threadIdx.x >> 5);
    int lane = threadIdx.x & 31;
    if (node >= N) return;
    const __half2* H2 = (const __half2*)Hh;   // row = 32 half2
    float ax = 0.f, ay = 0.f;
    int o0 = offs[node], o1 = offs[node + 1];
    int e = o0;
    for (; e + 4 <= o1; e += 4) {
        int s0 = csr[e], s1 = csr[e + 1], s2 = csr[e + 2], s3 = csr[e + 3];
        float2 f0 = __half22float2(H2[(size_t)s0 * 32 + lane]);
        float2 f1 = __half22float2(H2[(size_t)s1 * 32 + lane]);
        float2 f2 = __half22float2(H2[(size_t)s2 * 32 + lane]);
        float2 f3 = __half22float2(H2[(size_t)s3 * 32 + lane]);
        ax += (f0.x + f1.x) + (f2.x + f3.x);
        ay += (f0.y + f1.y) + (f2.y + f3.y);
    }
    for (; e < o1; ++e) {
        float2 f0 = __half22float2(H2[(size_t)csr[e] * 32 + lane]);
        ax += f0.x; ay += f0.y;
    }
    float2 fs = __half22float2(H2[(size_t)node * 32 + lane]);
    float di = dinv[node];
    float2 bv = ((const float2*)bias)[lane];
    float vx = di * (ax + fs.x) + bv.x;
    float vy = di * (ay + fs.y) + bv.y;
    if (RELU) { vx = vx > 0.f ? vx : 0.2f * vx; vy = vy > 0.f ? vy : 0.2f * vy; }
    ((float2*)Y)[(size_t)node * 32 + lane] = make_float2(vx, vy);
}

extern "C" void kernel_launch(void* const* d_in, const int* in_sizes, int n_in,
                              void* d_out, int out_size, void* d_ws, size_t ws_size,
                              hipStream_t stream) {
    const float* x  = (const float*)d_in[0];
    const int*   ei = (const int*)d_in[1];
    const float* W1 = (const float*)d_in[2];
    const float* b1 = (const float*)d_in[3];
    const float* W2 = (const float*)d_in[4];
    const float* b2 = (const float*)d_in[5];
    const float* W3 = (const float*)d_in[6];
    const float* b3 = (const float*)d_in[7];

    const int N = in_sizes[0] / 512;
    const int E = in_sizes[1] / 2;
    const int nb = (N + 255) / 256;

    char* w = (char*)d_ws;
    auto take = [&](size_t bytes) -> char* {
        char* p = w;
        w += alignup(bytes, 256);
        return p;
    };
    int*    flag  = (int*)take(256);
    int*    deg   = (int*)take((size_t)N * 4);
    int*    cnt   = (int*)take((size_t)N * 4);
    int*    offs  = (int*)take((size_t)(N + 1) * 4);
    int*    bsums = (int*)take((size_t)nb * 4);
    int*    boffs = (int*)take((size_t)nb * 4);
    int*    csr   = (int*)take((size_t)E * 4);
    float*  dinv  = (float*)take((size_t)N * 4);
    __half* bufA  = (__half*)take((size_t)N * 128 * 2);   // H' fp16
    float*  bufB  = (float*)take((size_t)N * 128 * 4);    // agg out f32
    u16*    w1h   = (u16*)take((size_t)512 * 128 * 2);
    u16*    w1l   = (u16*)take((size_t)512 * 128 * 2);
    u16*    w2h   = (u16*)take((size_t)128 * 64 * 2);
    u16*    w2l   = (u16*)take((size_t)128 * 64 * 2);
    u16*    w3h   = (u16*)take((size_t)64 * 64 * 2);
    u16*    w3l   = (u16*)take((size_t)64 * 64 * 2);

    const int TB = 256;
    // preprocessing
    k_detect<<<1, 64, 0, stream>>>(ei, flag);
    k_zero2<<<(N + TB - 1) / TB, TB, 0, stream>>>(deg, cnt, N);
    k_deg<<<(E + TB - 1) / TB, TB, 0, stream>>>(ei, E, flag, deg);
    k_dinv<<<(N + TB - 1) / TB, TB, 0, stream>>>(deg, dinv, N);
    k_scan1<<<nb, 256, 0, stream>>>(deg, offs, bsums, N);
    k_scan2<<<1, 256, 0, stream>>>(bsums, boffs, nb);
    k_scan3<<<(N + TB - 1) / TB, TB, 0, stream>>>(offs, boffs, N, E);
    k_fill<<<(E + TB - 1) / TB, TB, 0, stream>>>(ei, E, flag, offs, cnt, csr);
    // W splits
    k_splitW<512, 128><<<(512 * 128 / 8 + 255) / 256, 256, 0, stream>>>(W1, w1h, w1l);
    k_splitW<128, 64><<<(128 * 64 / 8 + 255) / 256, 256, 0, stream>>>(W2, w2h, w2l);
    k_splitW<64, 64><<<(64 * 64 / 8 + 255) / 256, 256, 0, stream>>>(W3, w3h, w3l);

    const int gemm_grid = (N + 63) / 64;
    // layer 1
    k_gemm_mfma<512, 128><<<gemm_grid, 128, 0, stream>>>(x, w1h, w1l, dinv, bufA, N);
    k_agg128<true><<<(N + 3) / 4, 256, 0, stream>>>(bufA, offs, csr, dinv, b1, bufB, N);
    // layer 2
    k_gemm_mfma<128, 64><<<gemm_grid, 64, 0, stream>>>(bufB, w2h, w2l, dinv, bufA, N);
    k_agg64<true><<<(N + 7) / 8, 256, 0, stream>>>(bufA, offs, csr, dinv, b2, bufB, N);
    // layer 3 (no relu), write straight to output
    k_gemm_mfma<64, 64><<<gemm_grid, 64, 0, stream>>>(bufB, w3h, w3l, dinv, bufA, N);
    k_agg64<false><<<(N + 7) / 8, 256, 0, stream>>>(bufA, offs, csr, dinv, b3,
                                                    (float*)d_out, N);
}

// Round 7
// 256.599 us; speedup vs baseline: 2.1116x; 1.0020x over previous
//
#include <hip/hip_runtime.h>
#include <hip/hip_fp16.h>

// ---------------------------------------------------------------------------
// GCN 3-layer forward on MI355X.
// detect edge layout -> deg -> dinv -> scan -> CSR fill -> W-split x3
//   -> [MFMA GEMM (bf16x3 split of f32) + dinv-scaled fp16 epilogue -> AGG] x3
// GEMM: no LDS/barriers. Wave tile 64x64 (MF=4,NF=4); 64-row blocks (grid 782).
//       Register double-buffer of BOTH A raw float4s AND B bf16 fragments:
//       issue A(t+1)+B(t+1) before split+MFMA of step t, so per-step load
//       latency is hidden behind the ~330-cyc compute phase (r6 post-mortem:
//       MFMA pipe was idle 88% waiting on same-step B loads).
// AGG:  per-dst gather of fp16 H' rows; F=128 wave/node, F=64 half-wave/node.
//       y = dinv_d*(sum H'[s] + H'[d]) + b  (dinv folded at both ends).
// ---------------------------------------------------------------------------

typedef __attribute__((ext_vector_type(8))) short bf16x8;
typedef __attribute__((ext_vector_type(4))) float f32x4;
typedef unsigned short u16;
typedef unsigned int u32;

static inline size_t alignup(size_t v, size_t a) { return (v + a - 1) & ~(a - 1); }

// pack top-16 bits of two f32 bit patterns into one u32 (lo half from b0)
__device__ __forceinline__ u32 pack_hi16(u32 b0, u32 b1) {
    return __builtin_amdgcn_perm(b1, b0, 0x07060302u);
}

// --- edge dtype detect: if input is int64, every odd 32-bit word is 0 -------
__global__ void k_detect(const int* __restrict__ ei, int* __restrict__ flag) {
    int v = ei[2 * threadIdx.x + 1];
    unsigned long long b = __ballot(v != 0);
    if (threadIdx.x == 0) *flag = (b == 0ull) ? 1 : 0;   // 1 => int64 layout
}

__global__ void k_zero2(int* __restrict__ a, int* __restrict__ b, int n) {
    int i = blockIdx.x * blockDim.x + threadIdx.x;
    if (i < n) { a[i] = 0; b[i] = 0; }
}

__global__ void k_deg(const int* __restrict__ ei, int E,
                      const int* __restrict__ flag, int* __restrict__ deg) {
    int i = blockIdx.x * blockDim.x + threadIdx.x;
    if (i >= E) return;
    int is64 = *flag;
    int d = is64 ? ei[2 * (E + i)] : ei[E + i];
    atomicAdd(&deg[d], 1);
}

__global__ void k_dinv(const int* __restrict__ deg, float* __restrict__ dinv, int N) {
    int i = blockIdx.x * blockDim.x + threadIdx.x;
    if (i < N) dinv[i] = rsqrtf((float)deg[i] + 1.0f);
}

// --- 3-kernel exclusive scan over deg (256 elems/block) ---------------------
__global__ void k_scan1(const int* __restrict__ deg, int* __restrict__ offs,
                        int* __restrict__ bsums, int N) {
    __shared__ int s[256];
    int i = blockIdx.x * 256 + threadIdx.x;
    int v = (i < N) ? deg[i] : 0;
    s[threadIdx.x] = v;
    __syncthreads();
    for (int off = 1; off < 256; off <<= 1) {
        int t = (threadIdx.x >= off) ? s[threadIdx.x - off] : 0;
        __syncthreads();
        s[threadIdx.x] += t;
        __syncthreads();
    }
    if (i < N) offs[i] = s[threadIdx.x] - v;   // exclusive
    if (threadIdx.x == 255) bsums[blockIdx.x] = s[255];
}

__global__ void k_scan2(const int* __restrict__ bsums, int* __restrict__ boffs, int nb) {
    __shared__ int s[256];
    int i = threadIdx.x;
    int v = (i < nb) ? bsums[i] : 0;
    s[i] = v;
    __syncthreads();
    for (int off = 1; off < 256; off <<= 1) {
        int t = (i >= off) ? s[i - off] : 0;
        __syncthreads();
        s[i] += t;
        __syncthreads();
    }
    if (i < nb) boffs[i] = s[i] - v;
}

__global__ void k_scan3(int* __restrict__ offs, const int* __restrict__ boffs,
                        int N, int E) {
    int i = blockIdx.x * blockDim.x + threadIdx.x;
    if (i < N) offs[i] += boffs[i >> 8];
    if (i == 0) offs[N] = E;
}

__global__ void k_fill(const int* __restrict__ ei, int E,
                       const int* __restrict__ flag,
                       const int* __restrict__ offs, int* __restrict__ cnt,
                       int* __restrict__ csr) {
    int i = blockIdx.x * blockDim.x + threadIdx.x;
    if (i >= E) return;
    int is64 = *flag;
    int s = is64 ? ei[2 * i] : ei[i];
    int d = is64 ? ei[2 * (E + i)] : ei[E + i];
    int slot = offs[d] + atomicAdd(&cnt[d], 1);
    csr[slot] = s;
}

// --- W pre-split into fragment-ordered bf16 hi/lo ----------------------------
// slot s = ((t*4+g)*F + c) holds W[t*32+g*8+j][c], j=0..7, as 8 bf16 (16 B).
template <int K, int F>
__global__ void k_splitW(const float* __restrict__ W, u16* __restrict__ Wh,
                         u16* __restrict__ Wl) {
    int s = blockIdx.x * 256 + threadIdx.x;
    if (s >= K * F / 8) return;
    int c = s % F;
    int kb = (s / F) * 8;
    union { u32 u[4]; bf16x8 v; } hi, lo;
#pragma unroll
    for (int p = 0; p < 4; p++) {
        float x0 = W[(size_t)(kb + 2 * p) * F + c];
        float x1 = W[(size_t)(kb + 2 * p + 1) * F + c];
        u32 b0 = __float_as_uint(x0), b1 = __float_as_uint(x1);
        float l0 = x0 - __uint_as_float(b0 & 0xFFFF0000u);
        float l1 = x1 - __uint_as_float(b1 & 0xFFFF0000u);
        hi.u[p] = pack_hi16(b0, b1);
        lo.u[p] = pack_hi16(__float_as_uint(l0), __float_as_uint(l1));
    }
    *(bf16x8*)(Wh + (size_t)s * 8) = hi.v;
    *(bf16x8*)(Wl + (size_t)s * 8) = lo.v;
}

// --- MFMA GEMM: H'[N,F] = dinv_row * (X[N,K] @ W[K,F]), fp16 out -------------
// One wave per 64-row x 64-col tile (MF=4, NF=4). Block = WNW waves covering
// F columns; grid = (N+63)/64. A AND B register double-buffered across K-steps.
template <int K, int F>
__global__ __launch_bounds__(F == 128 ? 128 : 64) void k_gemm_mfma(
        const float* __restrict__ X,
        const u16* __restrict__ Wh, const u16* __restrict__ Wl,
        const float* __restrict__ dinv, __half* __restrict__ Hh, int N) {
    constexpr int WNW = F / 64;        // waves per block (column slices)
    constexpr int MF = 4;
    constexpr int NF = 4;
    constexpr int NT = K / 32;         // K-steps
    const int tid = threadIdx.x;
    const int lane = tid & 63;
    const int wn = tid >> 6;           // 0..WNW-1
    const int lg = lane >> 4, li = lane & 15;
    const int row0 = blockIdx.x * 64;
    const int colbase = wn * 64;

    const float* xrow[MF];
#pragma unroll
    for (int m = 0; m < MF; m++) {
        int r = row0 + m * 16 + li;
        xrow[m] = X + (size_t)(r < N ? r : N - 1) * K;
    }

    f32x4 acc[MF][NF];
#pragma unroll
    for (int m = 0; m < MF; m++)
#pragma unroll
        for (int n = 0; n < NF; n++) acc[m][n] = (f32x4){0.f, 0.f, 0.f, 0.f};

    // prologue: raw A(0) and B(0)
    float4 acur[MF][2];
#pragma unroll
    for (int m = 0; m < MF; m++) {
        const float* p = xrow[m] + lg * 8;
        acur[m][0] = *(const float4*)p;
        acur[m][1] = *(const float4*)(p + 4);
    }
    bf16x8 bh[NF], bl[NF];
    {
        size_t slot0 = (size_t)lg * F + colbase + li;
#pragma unroll
        for (int n = 0; n < NF; n++) {
            bh[n] = *(const bf16x8*)(Wh + (slot0 + n * 16) * 8);
            bl[n] = *(const bf16x8*)(Wl + (slot0 + n * 16) * 8);
        }
    }

#pragma unroll 2
    for (int t = 0; t < NT; t++) {
        // prefetch A(t+1) and B(t+1): issue loads NOW, consume next iteration
        float4 anxt[MF][2];
        bf16x8 bhn[NF], bln[NF];
        if (t + 1 < NT) {
            size_t slot1 = (size_t)((t + 1) * 4 + lg) * F + colbase + li;
#pragma unroll
            for (int n = 0; n < NF; n++) {
                bhn[n] = *(const bf16x8*)(Wh + (slot1 + n * 16) * 8);
                bln[n] = *(const bf16x8*)(Wl + (slot1 + n * 16) * 8);
            }
#pragma unroll
            for (int m = 0; m < MF; m++) {
                const float* p = xrow[m] + (t + 1) * 32 + lg * 8;
                anxt[m][0] = *(const float4*)p;
                anxt[m][1] = *(const float4*)(p + 4);
            }
        }
        // split acur -> hi/lo bf16x8 (VALU; depends only on last-iter loads)
        bf16x8 ah[MF], al[MF];
#pragma unroll
        for (int m = 0; m < MF; m++) {
            float xv[8] = {acur[m][0].x, acur[m][0].y, acur[m][0].z, acur[m][0].w,
                           acur[m][1].x, acur[m][1].y, acur[m][1].z, acur[m][1].w};
            union { u32 u[4]; bf16x8 v; } hi, lo;
#pragma unroll
            for (int q = 0; q < 4; q++) {
                u32 b0 = __float_as_uint(xv[2 * q]);
                u32 b1 = __float_as_uint(xv[2 * q + 1]);
                float l0 = xv[2 * q]     - __uint_as_float(b0 & 0xFFFF0000u);
                float l1 = xv[2 * q + 1] - __uint_as_float(b1 & 0xFFFF0000u);
                hi.u[q] = pack_hi16(b0, b1);
                lo.u[q] = pack_hi16(__float_as_uint(l0), __float_as_uint(l1));
            }
            ah[m] = hi.v;
            al[m] = lo.v;
        }
        // 3-product accumulation: xh*wh + xh*wl + xl*wh (uses last-iter B)
#pragma unroll
        for (int m = 0; m < MF; m++)
#pragma unroll
            for (int n = 0; n < NF; n++) {
                acc[m][n] = __builtin_amdgcn_mfma_f32_16x16x32_bf16(ah[m], bh[n], acc[m][n], 0, 0, 0);
                acc[m][n] = __builtin_amdgcn_mfma_f32_16x16x32_bf16(ah[m], bl[n], acc[m][n], 0, 0, 0);
                acc[m][n] = __builtin_amdgcn_mfma_f32_16x16x32_bf16(al[m], bh[n], acc[m][n], 0, 0, 0);
            }
        // rotate A and B buffers (unrolled loop renames registers)
#pragma unroll
        for (int m = 0; m < MF; m++) {
            acur[m][0] = anxt[m][0];
            acur[m][1] = anxt[m][1];
        }
#pragma unroll
        for (int n = 0; n < NF; n++) {
            bh[n] = bhn[n];
            bl[n] = bln[n];
        }
    }

    // C/D layout: col = lane&15, row = (lane>>4)*4 + reg (m89-verified)
    // Epilogue folds dinv[row] and converts to fp16.
#pragma unroll
    for (int m = 0; m < MF; m++) {
        int rb = row0 + m * 16 + lg * 4;
#pragma unroll
        for (int r = 0; r < 4; r++) {
            int gr = rb + r;
            if (gr >= N) continue;
            float di = dinv[gr];
#pragma unroll
            for (int n = 0; n < NF; n++) {
                int col = colbase + n * 16 + li;
                Hh[(size_t)gr * F + col] = __float2half(acc[m][n][r] * di);
            }
        }
    }
}

// --- aggregation, F=128, fp16 H' in, f32 out ---------------------------------
// y = act(dinv_d * (sum_s H'[s] + H'[d]) + b); one wave per node; 4-edge unroll.
template <bool RELU>
__global__ __launch_bounds__(256) void k_agg128(const __half* __restrict__ Hh,
                                                const int* __restrict__ offs,
                                                const int* __restrict__ csr,
                                                const float* __restrict__ dinv,
                                                const float* __restrict__ bias,
                                                float* __restrict__ Y, int N) {
    int node = blockIdx.x * 4 + (threadIdx.x >> 6);
    int lane = threadIdx.x & 63;
    if (node >= N) return;
    const __half2* H2 = (const __half2*)Hh;   // row = 64 half2
    float ax = 0.f, ay = 0.f;
    int o0 = offs[node], o1 = offs[node + 1];
    int e = o0;
    for (; e + 4 <= o1; e += 4) {
        int s0 = csr[e], s1 = csr[e + 1], s2 = csr[e + 2], s3 = csr[e + 3];
        __half2 v0 = H2[(size_t)s0 * 64 + lane];
        __half2 v1 = H2[(size_t)s1 * 64 + lane];
        __half2 v2 = H2[(size_t)s2 * 64 + lane];
        __half2 v3 = H2[(size_t)s3 * 64 + lane];
        float2 f0 = __half22float2(v0), f1 = __half22float2(v1);
        float2 f2 = __half22float2(v2), f3 = __half22float2(v3);
        ax += (f0.x + f1.x) + (f2.x + f3.x);
        ay += (f0.y + f1.y) + (f2.y + f3.y);
    }
    for (; e < o1; ++e) {
        float2 f0 = __half22float2(H2[(size_t)csr[e] * 64 + lane]);
        ax += f0.x; ay += f0.y;
    }
    float2 fs = __half22float2(H2[(size_t)node * 64 + lane]);
    float di = dinv[node];
    float2 bv = ((const float2*)bias)[lane];
    float vx = di * (ax + fs.x) + bv.x;
    float vy = di * (ay + fs.y) + bv.y;
    if (RELU) { vx = vx > 0.f ? vx : 0.2f * vx; vy = vy > 0.f ? vy : 0.2f * vy; }
    ((float2*)Y)[(size_t)node * 64 + lane] = make_float2(vx, vy);
}

// --- aggregation, F=64, fp16 H' in, f32 out ----------------------------------
// Half-wave (32 lanes) per node: fp16 row = 128 B = 32 x half2. 8 nodes/block.
template <bool RELU>
__global__ __launch_bounds__(256) void k_agg64(const __half* __restrict__ Hh,
                                               const int* __restrict__ offs,
                                               const int* __restrict__ csr,
                                               const float* __restrict__ dinv,
                                               const float* __restrict__ bias,
                                               float* __restrict__ Y, int N) {
    int node = blockIdx.x * 8 + (threadIdx.x >> 5);
    int lane = threadIdx.x & 31;
    if (node >= N) return;
    const __half2* H2 = (const __half2*)Hh;   // row = 32 half2
    float ax = 0.f, ay = 0.f;
    int o0 = offs[node], o1 = offs[node + 1];
    int e = o0;
    for (; e + 4 <= o1; e += 4) {
        int s0 = csr[e], s1 = csr[e + 1], s2 = csr[e + 2], s3 = csr[e + 3];
        float2 f0 = __half22float2(H2[(size_t)s0 * 32 + lane]);
        float2 f1 = __half22float2(H2[(size_t)s1 * 32 + lane]);
        float2 f2 = __half22float2(H2[(size_t)s2 * 32 + lane]);
        float2 f3 = __half22float2(H2[(size_t)s3 * 32 + lane]);
        ax += (f0.x + f1.x) + (f2.x + f3.x);
        ay += (f0.y + f1.y) + (f2.y + f3.y);
    }
    for (; e < o1; ++e) {
        float2 f0 = __half22float2(H2[(size_t)csr[e] * 32 + lane]);
        ax += f0.x; ay += f0.y;
    }
    float2 fs = __half22float2(H2[(size_t)node * 32 + lane]);
    float di = dinv[node];
    float2 bv = ((const float2*)bias)[lane];
    float vx = di * (ax + fs.x) + bv.x;
    float vy = di * (ay + fs.y) + bv.y;
    if (RELU) { vx = vx > 0.f ? vx : 0.2f * vx; vy = vy > 0.f ? vy : 0.2f * vy; }
    ((float2*)Y)[(size_t)node * 32 + lane] = make_float2(vx, vy);
}

extern "C" void kernel_launch(void* const* d_in, const int* in_sizes, int n_in,
                              void* d_out, int out_size, void* d_ws, size_t ws_size,
                              hipStream_t stream) {
    const float* x  = (const float*)d_in[0];
    const int*   ei = (const int*)d_in[1];
    const float* W1 = (const float*)d_in[2];
    const float* b1 = (const float*)d_in[3];
    const float* W2 = (const float*)d_in[4];
    const float* b2 = (const float*)d_in[5];
    const float* W3 = (const float*)d_in[6];
    const float* b3 = (const float*)d_in[7];

    const int N = in_sizes[0] / 512;
    const int E = in_sizes[1] / 2;
    const int nb = (N + 255) / 256;

    char* w = (char*)d_ws;
    auto take = [&](size_t bytes) -> char* {
        char* p = w;
        w += alignup(bytes, 256);
        return p;
    };
    int*    flag  = (int*)take(256);
    int*    deg   = (int*)take((size_t)N * 4);
    int*    cnt   = (int*)take((size_t)N * 4);
    int*    offs  = (int*)take((size_t)(N + 1) * 4);
    int*    bsums = (int*)take((size_t)nb * 4);
    int*    boffs = (int*)take((size_t)nb * 4);
    int*    csr   = (int*)take((size_t)E * 4);
    float*  dinv  = (float*)take((size_t)N * 4);
    __half* bufA  = (__half*)take((size_t)N * 128 * 2);   // H' fp16
    float*  bufB  = (float*)take((size_t)N * 128 * 4);    // agg out f32
    u16*    w1h   = (u16*)take((size_t)512 * 128 * 2);
    u16*    w1l   = (u16*)take((size_t)512 * 128 * 2);
    u16*    w2h   = (u16*)take((size_t)128 * 64 * 2);
    u16*    w2l   = (u16*)take((size_t)128 * 64 * 2);
    u16*    w3h   = (u16*)take((size_t)64 * 64 * 2);
    u16*    w3l   = (u16*)take((size_t)64 * 64 * 2);

    const int TB = 256;
    // preprocessing
    k_detect<<<1, 64, 0, stream>>>(ei, flag);
    k_zero2<<<(N + TB - 1) / TB, TB, 0, stream>>>(deg, cnt, N);
    k_deg<<<(E + TB - 1) / TB, TB, 0, stream>>>(ei, E, flag, deg);
    k_dinv<<<(N + TB - 1) / TB, TB, 0, stream>>>(deg, dinv, N);
    k_scan1<<<nb, 256, 0, stream>>>(deg, offs, bsums, N);
    k_scan2<<<1, 256, 0, stream>>>(bsums, boffs, nb);
    k_scan3<<<(N + TB - 1) / TB, TB, 0, stream>>>(offs, boffs, N, E);
    k_fill<<<(E + TB - 1) / TB, TB, 0, stream>>>(ei, E, flag, offs, cnt, csr);
    // W splits
    k_splitW<512, 128><<<(512 * 128 / 8 + 255) / 256, 256, 0, stream>>>(W1, w1h, w1l);
    k_splitW<128, 64><<<(128 * 64 / 8 + 255) / 256, 256, 0, stream>>>(W2, w2h, w2l);
    k_splitW<64, 64><<<(64 * 64 / 8 + 255) / 256, 256, 0, stream>>>(W3, w3h, w3l);

    const int gemm_grid = (N + 63) / 64;
    // layer 1
    k_gemm_mfma<512, 128><<<gemm_grid, 128, 0, stream>>>(x, w1h, w1l, dinv, bufA, N);
    k_agg128<true><<<(N + 3) / 4, 256, 0, stream>>>(bufA, offs, csr, dinv, b1, bufB, N);
    // layer 2
    k_gemm_mfma<128, 64><<<gemm_grid, 64, 0, stream>>>(bufB, w2h, w2l, dinv, bufA, N);
    k_agg64<true><<<(N + 7) / 8, 256, 0, stream>>>(bufA, offs, csr, dinv, b2, bufB, N);
    // layer 3 (no relu), write straight to output
    k_gemm_mfma<64, 64><<<gemm_grid, 64, 0, stream>>>(bufB, w3h, w3l, dinv, bufA, N);
    k_agg64<false><<<(N + 7) / 8, 256, 0, stream>>>(bufA, offs, csr, dinv, b3,
                                                    (float*)d_out, N);
}